// Round 7
// baseline (2311.838 us; speedup 1.0000x reference)
//
#include <hip/hip_runtime.h>

// ---------------------------------------------------------------------------
// AppUsageFEDformer forward on MI355X (gfx950).
// embed -> 2x [Wq gemm(->qT bf16) -> DFT-GEMM -> mix -> iDFT-GEMM ->
//              Wo gemm(+res) -> decomp -> conv1(relu) -> conv2(+res) -> decomp]
//          -> layernorm(+L-mean sub) -> last-token concat -> proj gemm.
// R17->R18: k_gemm4 = geometry fix.  R17 accounting: block-iter 1875 cyc =
// MFMA 620 + LDS (64KB rd + 24KB gll wr ~ 785 @112B/cyc) + VALU 490 -- pipes
// serialized, and 64x64/wave needs 704 LDS-B per MFMA (pipe can't feed >30%).
// Fix: 256 threads, 4 waves of 128x64 (375 B/MFMA incl. staging), tile
// 256x128, BK=32, TWO LDS buffers = 48KB -> 3 blocks/CU; lead-1 gll staging
// (FETCH shows ~85% L2-hit => ~225cyc loads, covered by one iter), one raw
// s_barrier + vmcnt(0) per iter (m97-proven at 3 blocks/CU), 12 ds_read ->
// 32 MFMA, setprio cluster.  Same XOR source swizzle, same swapped-MFMA
// packed epilogue, same k-ascending MFMA order -> bit-identical output.
// k_gemm (128^2) kept for DFT/iDFT/proj shapes.
// ---------------------------------------------------------------------------

typedef unsigned short u16;
typedef float f32x4 __attribute__((ext_vector_type(4)));
typedef __bf16 bf16x8 __attribute__((ext_vector_type(8)));

__device__ __forceinline__ u16 f2b(float f) {
  unsigned u = __float_as_uint(f);
  return (u16)((u + 0x7FFFu + ((u >> 16) & 1u)) >> 16);
}
__device__ __forceinline__ float b2f(u16 v) {
  return __uint_as_float((unsigned)v << 16);
}
__device__ __forceinline__ f32x4 b4f(ushort4 v) {
  f32x4 r;
  r.x = b2f(v.x); r.y = b2f(v.y); r.z = b2f(v.z); r.w = b2f(v.w);
  return r;
}

__device__ __forceinline__ void gll16(const void* g, void* l) {
  __builtin_amdgcn_global_load_lds(
      (const __attribute__((address_space(1))) void*)g,
      (__attribute__((address_space(3))) void*)l, 16, 0, 0);
}

// SWAP=true computes mfma(b,a): D'[n][m] = sum_k B[n][k]A[m][k] = C[m][n];
// lane then holds row m = lane&15, cols n = (lane>>4)*4+e.  Values are the
// same dot products in the same HW order -> bit-identical per element.
template<bool SWAP>
__device__ __forceinline__ f32x4 mfma16(bf16x8 a, bf16x8 b, f32x4 c) {
  if constexpr (SWAP)
    return __builtin_amdgcn_mfma_f32_16x16x32_bf16(b, a, c, 0, 0, 0);
  else
    return __builtin_amdgcn_mfma_f32_16x16x32_bf16(a, b, c, 0, 0, 0);
}

// ---------------- bf16 MFMA GEMM:  C = A(MxK) * B(NxK)^T (+bias)(+res)(relu)
// 128x128 tile, BK=32.  R9-proven scalar-register 1-deep pipeline.  Kept for
// small/odd shapes (DFT N=64 guard, iDFT K=64, proj M=64 K=544).
// Epilogue packs 4 values per store (swapped MFMA for !TRANS).
template<bool BIAS, bool RELU, bool RES, bool OUTBF16, bool GUARD, bool TRANS,
         bool SWZ>
__global__ __launch_bounds__(256, 3)
void k_gemm(const u16* __restrict__ A, const u16* __restrict__ B,
            const float* __restrict__ bias, const u16* __restrict__ res,
            float* __restrict__ Cf, u16* __restrict__ Cb,
            int M, int N, int K,
            long zA, long zB, long zC, int nbn, int nbm)
{
  __shared__ __align__(16) u16 sA[2][128 * 32];
  __shared__ __align__(16) u16 sB[2][128 * 32];
  const int tid = threadIdx.x;
  const int wave = tid >> 6, lane = tid & 63;
  int bn, bm;
  if (SWZ) {
    int bid = blockIdx.x;
    int xcd = bid & 7, loc = bid >> 3;
    bn = loc % nbn;
    bm = xcd * (nbm >> 3) + loc / nbn;
  } else {
    bn = blockIdx.x;
    bm = blockIdx.y;
  }
  const int bz = blockIdx.z;
  const int wm = (wave >> 1) * 64, wn = (wave & 1) * 64;

  A += (size_t)bz * zA;
  B += (size_t)bz * zB;

  const int r0 = tid >> 2;              // row 0..63 (row1 = r0+64)
  const int lg = tid & 3;               // logical 16B group
  const int ps = lg ^ ((r0 >> 1) & 3);  // physical group (same for r0,r0+64)
  int gmA0 = bm * 128 + r0, gmA1 = gmA0 + 64;
  int gnB0 = bn * 128 + r0, gnB1 = gnB0 + 64;
  if (GUARD) {
    gmA0 = gmA0 < M ? gmA0 : M - 1;
    gmA1 = gmA1 < M ? gmA1 : M - 1;
    gnB0 = gnB0 < N ? gnB0 : N - 1;
    gnB1 = gnB1 < N ? gnB1 : N - 1;
  }
  const size_t rb = (size_t)K * 2;
  const char* pa0 = (const char*)A + (size_t)gmA0 * rb + lg * 16;
  const char* pa1 = (const char*)A + (size_t)gmA1 * rb + lg * 16;
  const char* pb0 = (const char*)B + (size_t)gnB0 * rb + lg * 16;
  const char* pb1 = (const char*)B + (size_t)gnB1 * rb + lg * 16;
  const int w0 = r0 * 32 + ps * 8;      // u16 offset in tile; row1 at +2048

  f32x4 acc[4][4];
  const f32x4 z = {0.f, 0.f, 0.f, 0.f};
#pragma unroll
  for (int i = 0; i < 4; ++i)
#pragma unroll
    for (int j = 0; j < 4; ++j) acc[i][j] = z;

  const int r = lane & 15, qd = lane >> 4;
  const int pA = (qd ^ ((lane >> 1) & 3)) * 8;   // fragment physical group
  const int nk = K >> 5;

  uint4 va0, va1, vb0, vb1;             // tile staged in SCALAR registers
  auto gload = [&](int kt) {
    const size_t ko = (size_t)kt * 64;
    va0 = *(const uint4*)(pa0 + ko);
    va1 = *(const uint4*)(pa1 + ko);
    vb0 = *(const uint4*)(pb0 + ko);
    vb1 = *(const uint4*)(pb1 + ko);
  };

  gload(0);
  int pg = 0;
  for (int kt = 0; kt < nk; ++kt) {
    *(uint4*)&sA[pg][w0]        = va0;
    *(uint4*)&sA[pg][w0 + 2048] = va1;
    *(uint4*)&sB[pg][w0]        = vb0;
    *(uint4*)&sB[pg][w0 + 2048] = vb1;
    if (kt + 1 < nk) gload(kt + 1);   // next tile flies during MFMA below
    __syncthreads();                  // drains lgkm (ds_write), not vmcnt
    bf16x8 af[4], bg[4];
#pragma unroll
    for (int mi = 0; mi < 4; ++mi)
      af[mi] = *(const bf16x8*)&sA[pg][(wm + mi * 16 + r) * 32 + pA];
#pragma unroll
    for (int ni = 0; ni < 4; ++ni)
      bg[ni] = *(const bf16x8*)&sB[pg][(wn + ni * 16 + r) * 32 + pA];
#pragma unroll
    for (int mi = 0; mi < 4; ++mi)
#pragma unroll
      for (int ni = 0; ni < 4; ++ni)
        acc[mi][ni] = mfma16<!TRANS>(af[mi], bg[ni], acc[mi][ni]);
    pg ^= 1;
  }

  if (Cf) Cf += (size_t)bz * zC;
  if (Cb) Cb += (size_t)bz * zC;

  if constexpr (!TRANS) {
    // swapped orientation: lane holds row gm = ..+r, 4 consecutive gn.
#pragma unroll
    for (int mi = 0; mi < 4; ++mi) {
      const int gm = bm * 128 + wm + mi * 16 + r;
      if (GUARD && gm >= M) continue;
#pragma unroll
      for (int ni = 0; ni < 4; ++ni) {
        const int gn0 = bn * 128 + wn + ni * 16 + qd * 4;
        if (GUARD && gn0 >= N) continue;
        float v[4];
        ushort4 rv;
        if (RES) rv = *(const ushort4*)&res[(size_t)gm * N + gn0];
#pragma unroll
        for (int e = 0; e < 4; ++e) {
          v[e] = acc[mi][ni][e];
          if (BIAS) v[e] += bias[gn0 + e];
          if (RES)  v[e] += b2f(e == 0 ? rv.x : e == 1 ? rv.y : e == 2 ? rv.z : rv.w);
          if (RELU) v[e] = v[e] > 0.f ? v[e] : 0.f;
        }
        if (OUTBF16) {
          ushort4 o;
          o.x = f2b(v[0]); o.y = f2b(v[1]); o.z = f2b(v[2]); o.w = f2b(v[3]);
          *(ushort4*)&Cb[(size_t)gm * N + gn0] = o;
        } else {
          float4 o = {v[0], v[1], v[2], v[3]};
          *(float4*)&Cf[(size_t)gm * N + gn0] = o;
        }
      }
    }
  } else {
    // original orientation: lane holds col gn = ..+r, 4 consecutive gm;
    // TRANS store C[gn*M + gm] packs along gm.
#pragma unroll
    for (int ni = 0; ni < 4; ++ni) {
      const int gn = bn * 128 + wn + ni * 16 + r;
      if (GUARD && gn >= N) continue;
      const float bb = BIAS ? bias[gn] : 0.f;
#pragma unroll
      for (int mi = 0; mi < 4; ++mi) {
        const int gm0 = bm * 128 + wm + mi * 16 + qd * 4;
        if (GUARD && gm0 >= M) continue;
        float v[4];
#pragma unroll
        for (int e = 0; e < 4; ++e) {
          v[e] = acc[mi][ni][e];
          if (BIAS) v[e] += bb;
          if (RELU) v[e] = v[e] > 0.f ? v[e] : 0.f;
        }
        if (OUTBF16) {
          ushort4 o;
          o.x = f2b(v[0]); o.y = f2b(v[1]); o.z = f2b(v[2]); o.w = f2b(v[3]);
          *(ushort4*)&Cb[(size_t)gn * M + gm0] = o;
        } else {
          float4 o = {v[0], v[1], v[2], v[3]};
          *(float4*)&Cf[(size_t)gn * M + gm0] = o;
        }
      }
    }
  }
}

// ---------------- 256x128 3-block/CU, 128x64-per-wave bf16 GEMM ------------
// C = A(MxK) * B(NxK)^T (+bias)(+res)(relu), bf16 out.  BM=256, BN=128,
// BK=32, 256 threads = 4 waves (2M x 2N), per-wave 128x64 (acc[8][4]).
// Requires M%256==0 (per batch), N%128==0, K%32==0, K>=64.
// LDS 48KB: sA[2][256x32] + sB[2][128x32] -> THREE blocks resident per CU.
// Per K-tile, ONE raw barrier:
//   vmcnt(0) [tile t landed; loads are ~85% L2-hit (~225cyc), issued one
//   full iter (~700cyc) earlier -> drain usually free; 3 resident blocks
//   cover the rest] | s_barrier | 12 ds_read (XOR-swizzled) | stage(t+1)
//   (6 gll16 into the buffer whose readers all completed before this
//   barrier) | setprio(1) 32 MFMA setprio(0).
// LDS traffic: 48KB rd + 24KB wr per 128 MFMA = 375 B/MFMA (was 704) --
// MFMA demand now >= LDS demand, so the matrix pipe can saturate.
// 1D grid, XCD-grouped decode.  Epilogue: packed 8-B stores (swapped MFMA).
template<bool BIAS, bool RELU, bool RES, bool TRANS>
__global__ __launch_bounds__(256, 3)
void k_gemm4(const u16* __restrict__ A, const u16* __restrict__ B,
             const float* __restrict__ bias, const u16* __restrict__ res,
             u16* __restrict__ C, int M, int N, int K,
             int nbn, int nbm, long zA, long zC)
{
  __shared__ __align__(16) u16 sA[2][256 * 32];
  __shared__ __align__(16) u16 sB[2][128 * 32];
  const int tid = threadIdx.x;
  const int w4 = tid >> 6, lane = tid & 63;
  const int bid = blockIdx.x;
  const int xcd = bid & 7, loc = bid >> 3;
  const int mpx = (int)(gridDim.x >> 3) / nbn;   // m-groups per XCD
  const int mflat = xcd * mpx + loc / nbn;
  const int bn = loc % nbn;
  const int bz = mflat / nbm;
  const int bm = mflat - bz * nbm;
  const int wm = (w4 >> 1) * 128, wn = (w4 & 1) * 64;

  A += (size_t)bz * zA;

  // staging: thread covers A rows r0+64j (j=0..3) and B rows r0, r0+64;
  // gll dest wave-uniform base (+ implicit lane*16B), XOR swizzle applied
  // to the GLOBAL source k-group (same for all row-blocks: +64 preserves
  // (r0>>1)&3).
  const int r0 = tid >> 2;                       // 0..63
  const int lg = (tid & 3) ^ ((r0 >> 1) & 3);
  const u16* pA0 = A + (size_t)(bm * 256 + r0) * K + lg * 8;
  const u16* pB0 = B + (size_t)(bn * 128 + r0) * K + lg * 8;
  const int wb = w4 * 512;                       // wave chunk base (u16)

  const int nk = K >> 5;

  auto stage = [&](int t, int sb) {
    const size_t ko = (size_t)t * 32;
#pragma unroll
    for (int j = 0; j < 4; ++j)
      gll16(pA0 + (size_t)(j * 64) * K + ko, &sA[sb][j * 2048 + wb]);
#pragma unroll
    for (int j = 0; j < 2; ++j)
      gll16(pB0 + (size_t)(j * 64) * K + ko, &sB[sb][j * 2048 + wb]);
  };

  f32x4 acc[8][4];
  const f32x4 z = {0.f, 0.f, 0.f, 0.f};
#pragma unroll
  for (int i = 0; i < 8; ++i)
#pragma unroll
    for (int j = 0; j < 4; ++j) acc[i][j] = z;

  const int fr = lane & 15, qd = lane >> 4;
  const int pAo = ((qd ^ ((lane >> 1) & 3)) << 3);   // fragment phys group

  stage(0, 0);
  for (int t = 0; t < nk; ++t) {
    const int cb = t & 1;
    asm volatile("s_waitcnt vmcnt(0)" ::: "memory");
    __builtin_amdgcn_s_barrier();     // all waves' tile-t stages landed
    asm volatile("" ::: "memory");
    const u16* bufA = &sA[cb][0];
    const u16* bufB = &sB[cb][0];
    bf16x8 af[8], bg[4];
#pragma unroll
    for (int i = 0; i < 8; ++i)
      af[i] = *(const bf16x8*)&bufA[(wm + i * 16 + fr) * 32 + pAo];
#pragma unroll
    for (int i = 0; i < 4; ++i)
      bg[i] = *(const bf16x8*)&bufB[(wn + i * 16 + fr) * 32 + pAo];
    if (t + 1 < nk) stage(t + 1, cb ^ 1);  // readers finished before barrier
    __builtin_amdgcn_s_setprio(1);
#pragma unroll
    for (int mi = 0; mi < 8; ++mi)
#pragma unroll
      for (int ni = 0; ni < 4; ++ni)
        acc[mi][ni] = mfma16<!TRANS>(af[mi], bg[ni], acc[mi][ni]);
    __builtin_amdgcn_s_setprio(0);
  }

  C += (size_t)bz * zC;

  if constexpr (!TRANS) {
    // swapped orientation: lane holds row gm = ..+fr, 4 consecutive gn.
#pragma unroll
    for (int mi = 0; mi < 8; ++mi) {
      const int gm = bm * 256 + wm + mi * 16 + fr;
#pragma unroll
      for (int ni = 0; ni < 4; ++ni) {
        const int gn0 = bn * 128 + wn + ni * 16 + qd * 4;
        float v[4];
        ushort4 rv;
        if (RES) rv = *(const ushort4*)&res[(size_t)gm * N + gn0];
#pragma unroll
        for (int e = 0; e < 4; ++e) {
          v[e] = acc[mi][ni][e];
          if (BIAS) v[e] += bias[gn0 + e];
          if (RES)  v[e] += b2f(e == 0 ? rv.x : e == 1 ? rv.y : e == 2 ? rv.z : rv.w);
          if (RELU) v[e] = v[e] > 0.f ? v[e] : 0.f;
        }
        ushort4 o;
        o.x = f2b(v[0]); o.y = f2b(v[1]); o.z = f2b(v[2]); o.w = f2b(v[3]);
        *(ushort4*)&C[(size_t)gm * N + gn0] = o;
      }
    }
  } else {
    // original orientation: lane holds col gn = ..+fr, 4 consecutive gm;
    // TRANS store C[gn*M + gm] packs along gm.
#pragma unroll
    for (int ni = 0; ni < 4; ++ni) {
      const int gn = bn * 128 + wn + ni * 16 + fr;
      const float bb = BIAS ? bias[gn] : 0.f;
#pragma unroll
      for (int mi = 0; mi < 8; ++mi) {
        const int gm0 = bm * 256 + wm + mi * 16 + qd * 4;
        float v[4];
#pragma unroll
        for (int e = 0; e < 4; ++e) {
          v[e] = acc[mi][ni][e];
          if (BIAS) v[e] += bb;
          if (RELU) v[e] = v[e] > 0.f ? v[e] : 0.f;
        }
        ushort4 o;
        o.x = f2b(v[0]); o.y = f2b(v[1]); o.z = f2b(v[2]); o.w = f2b(v[3]);
        *(ushort4*)&C[(size_t)gn * M + gm0] = o;
      }
    }
  }
}

// ---------------- misc small kernels ----------------
__global__ void k_basis(u16* __restrict__ dftB, u16* __restrict__ Binv)
{
  int id = blockIdx.x * 256 + threadIdx.x;  // 32768
  if (id >= 32768) return;
  {
    int m = id >> 9, l = id & 511;
    int mm = m & 31;
    float ang = (float)((l * mm) & 511) * (6.283185307179586f / 512.f);
    float s, c;
    __sincosf(ang, &s, &c);
    dftB[id] = f2b(m < 32 ? c : -s);
  }
  {
    int l = id >> 6, m = id & 63;
    int mm = m & 31;
    float ang = (float)((l * mm) & 511) * (6.283185307179586f / 512.f);
    float s, c;
    __sincosf(ang, &s, &c);
    float v;
    if (m < 32) v = (m == 0 ? 1.f : 2.f) * (1.f / 512.f) * c;
    else        v = (mm == 0 ? 0.f : (-2.f / 512.f) * s);
    Binv[id] = f2b(v);
  }
}

__global__ void k_convert(const float* __restrict__ in, u16* __restrict__ out, int n)
{
  int id = blockIdx.x * 256 + threadIdx.x;
  if (id < n) out[id] = f2b(in[id]);
}

__global__ void k_convproj(const float* __restrict__ w, u16* __restrict__ o)
{
  int id = blockIdx.x * 256 + threadIdx.x;  // 10000*544
  if (id >= 10000 * 544) return;
  int n = id / 544, k = id % 544;
  o[id] = f2b(k < 536 ? w[(size_t)n * 536 + k] : 0.f);
}

// weight transpose for mode mix: wrT[((l*8+h)*32+m)][i][o], LDS pad 33.
__global__ void k_transp(const float* __restrict__ wr, const float* __restrict__ wi,
                         float* __restrict__ wrT, float* __restrict__ wiT)
{
  __shared__ float tr[64 * 33], ti[64 * 33];
  int blk = blockIdx.x;            // (l*8+h)*64+i, 1024 blocks
  int t = threadIdx.x;
  int lh = blk >> 6, i = blk & 63;
  const size_t src = (size_t)blk * 2048;   // o*32+m slab
#pragma unroll
  for (int p = 0; p < 8; ++p) {
    int id = p * 256 + t;
    int o = id >> 5, m = id & 31;
    tr[o * 33 + m] = wr[src + id];
    ti[o * 33 + m] = wi[src + id];
  }
  __syncthreads();
#pragma unroll
  for (int p = 0; p < 8; ++p) {
    int id = p * 256 + t;
    int m = id >> 6, o = id & 63;
    size_t dst = ((size_t)(lh * 32 + m) * 64 + i) * 64 + o;
    wrT[dst] = tr[o * 33 + m];
    wiT[dst] = ti[o * 33 + m];
  }
}

__global__ void k_embed(const int* __restrict__ xapp, const float* __restrict__ xtime,
                        const float* __restrict__ emb, const float* __restrict__ tw,
                        const float* __restrict__ tb, u16* __restrict__ xb)
{
  int id = blockIdx.x * 256 + threadIdx.x;  // B*L*128 (float4 lanes)
  int j = id & 127, bl = id >> 7;
  float4 e = ((const float4*)emb)[(size_t)xapp[bl] * 128 + j];
  float t = xtime[bl];
  float4 w4 = ((const float4*)tw)[j];
  float4 b4 = ((const float4*)tb)[j];
  ushort4 o;
  o.x = f2b(e.x + t * w4.x + b4.x);
  o.y = f2b(e.y + t * w4.y + b4.y);
  o.z = f2b(e.z + t * w4.z + b4.z);
  o.w = f2b(e.w + t * w4.w + b4.w);
  ((ushort4*)xb)[id] = o;
}

// mode mix: coef[b*512 + h*64+o][m](Re) / [32+m](Im), bf16 A-operand.
__global__ __launch_bounds__(256)
void k_mix(const float* __restrict__ spec, const float* __restrict__ wrT,
           const float* __restrict__ wiT, u16* __restrict__ Ab)
{
  __shared__ float swr[4096], swi[4096];   // [i*64+o]
  __shared__ float sre[4][64], sim[4][64]; // [bsub][i]
  int hm = blockIdx.x;                     // h*32+m
  int bg = blockIdx.y;                     // 0..3
  int h = hm >> 5, m = hm & 31, t = threadIdx.x;
  const float* wrb = wrT + (size_t)hm * 4096;
  const float* wib = wiT + (size_t)hm * 4096;
#pragma unroll
  for (int p = 0; p < 16; ++p) {
    int id = p * 256 + t;
    swr[id] = wrb[id];
    swi[id] = wib[id];
  }
  int o = t & 63, bsub = t >> 6;
  for (int b0 = 0; b0 < 16; b0 += 4) {
    __syncthreads();
    int b = bg * 16 + b0 + bsub;
    const float* spb = spec + (size_t)b * 32768;
    sre[bsub][o] = spb[m * 512 + h * 64 + o];
    sim[bsub][o] = spb[(32 + m) * 512 + h * 64 + o];
    __syncthreads();
    float aR = 0.f, aI = 0.f;
#pragma unroll 8
    for (int i = 0; i < 64; ++i) {
      float xr = sre[bsub][i], xi = sim[bsub][i];
      float wrv = swr[i * 64 + o], wiv = swi[i * 64 + o];
      aR += xr * wrv - xi * wiv;
      aI += xr * wiv + xi * wrv;
    }
    size_t row = (size_t)b * 512 + h * 64 + o;
    Ab[row * 64 + m] = f2b(aR);
    Ab[row * 64 + 32 + m] = f2b(aI);
  }
}

// series_decomp: out = x - movavg_25(x), edge-padded.  bf16 in/out, fp32
// accumulate.  XCD-grouped: all blocks of batch b run on XCD b%8.
__global__ void k_decomp(const u16* __restrict__ in, u16* __restrict__ outb)
{
  int blk = blockIdx.x;                 // 512 blocks
  int j = blk >> 3;
  int b = (blk & 7) + 8 * (j >> 3);     // xcd = b%8
  int ck = (j & 7) * 2 + (threadIdx.x >> 7);
  int d4 = threadIdx.x & 127;
  const ushort4* xb = (const ushort4*)(in + (size_t)b * 262144) + d4;
  ushort4* ob = (ushort4*)(outb + (size_t)b * 262144) + d4;
  int l0 = ck * 32;
  f32x4 sum = {0.f, 0.f, 0.f, 0.f};
#pragma unroll
  for (int jj = -12; jj <= 12; ++jj) {
    int idx = l0 + jj;
    idx = idx < 0 ? 0 : idx;
    sum += b4f(xb[idx * 128]);
  }
#pragma unroll 4
  for (int l = l0; l < l0 + 32; ++l) {
    f32x4 xv = b4f(xb[l * 128]);
    f32x4 o = xv - sum * (1.f / 25.f);
    ushort4 ov;
    ov.x = f2b(o.x); ov.y = f2b(o.y); ov.z = f2b(o.z); ov.w = f2b(o.w);
    ob[l * 128] = ov;
    int ia = l + 13 > 511 ? 511 : l + 13;
    int ir = l - 12 < 0 ? 0 : l - 12;
    sum += b4f(xb[ia * 128]) - b4f(xb[ir * 128]);
  }
}

__global__ void k_lnstats(const u16* __restrict__ x, float* __restrict__ mu,
                          float* __restrict__ rs)
{
  int row = blockIdx.x;
  const u16* xr = x + (size_t)row * 512;
  int t = threadIdx.x;
  ushort2 p = ((const ushort2*)xr)[t];
  float v0 = b2f(p.x), v1 = b2f(p.y);
  float s = v0 + v1, ss = v0 * v0 + v1 * v1;
#pragma unroll
  for (int off = 32; off; off >>= 1) {
    s += __shfl_down(s, off);
    ss += __shfl_down(ss, off);
  }
  __shared__ float as[4], ass[4];
  if ((t & 63) == 0) { as[t >> 6] = s; ass[t >> 6] = ss; }
  __syncthreads();
  if (t == 0) {
    float S = as[0] + as[1] + as[2] + as[3];
    float SS = ass[0] + ass[1] + ass[2] + ass[3];
    float m = S * (1.f / 512.f);
    float var = SS * (1.f / 512.f) - m * m;
    mu[row] = m;
    rs[row] = rsqrtf(var + 1e-5f);
  }
}

// lastcat pass 1: partial[b][g][d] = sum_{l in g*64..} (x-mu)*rs  (512 blocks)
__global__ void k_lastcat1(const u16* __restrict__ x, const float* __restrict__ mu,
                           const float* __restrict__ rs, float* __restrict__ part)
{
  int b = blockIdx.x >> 3, g = blockIdx.x & 7, t = threadIdx.x;
  const u16* xb = x + (size_t)b * 262144;
  const float* mub = mu + b * 512;
  const float* rsb = rs + b * 512;
  float a0 = 0.f, a1 = 0.f;
#pragma unroll 4
  for (int l = g * 64; l < g * 64 + 64; ++l) {
    float m = mub[l], rr = rsb[l];
    ushort2 p = ((const ushort2*)(xb + l * 512))[t];
    a0 += (b2f(p.x) - m) * rr;
    a1 += (b2f(p.y) - m) * rr;
  }
  part[((size_t)b * 8 + g) * 512 + 2 * t]     = a0;
  part[((size_t)b * 8 + g) * 512 + 2 * t + 1] = a1;
}

// lastcat pass 2: cat[b][d] = nw[d]*(ln_last - mean_l);  norm_b cancels.
__global__ void k_lastcat2(const u16* __restrict__ x, const float* __restrict__ mu,
                           const float* __restrict__ rs, const float* __restrict__ part,
                           const float* __restrict__ nw, u16* __restrict__ cat)
{
  int b = blockIdx.x, t = threadIdx.x;
#pragma unroll
  for (int hh = 0; hh < 2; ++hh) {
    int d = t + hh * 256;
    float acc = 0.f;
#pragma unroll
    for (int g = 0; g < 8; ++g)
      acc += part[((size_t)b * 8 + g) * 512 + d];
    float lastv = (b2f(x[(size_t)b * 262144 + 511 * 512 + d]) - mu[b * 512 + 511])
                  * rs[b * 512 + 511];
    cat[b * 544 + d] = f2b(nw[d] * (lastv - acc * (1.f / 512.f)));
  }
}

__global__ void k_timecat(const float* __restrict__ tv, u16* __restrict__ cat)
{
  int id = blockIdx.x * 256 + threadIdx.x;  // 64*32
  if (id >= 2048) return;
  int b = id >> 5, j = id & 31;
  int pos = 512 + j;
  float v = (pos < 536) ? tv[((size_t)b * 512 + 511) * 24 + (pos - 512)] : 0.f;
  cat[b * 544 + pos] = f2b(v);
}

// ---------------------------------------------------------------------------
extern "C" void kernel_launch(void* const* d_in, const int* in_sizes, int n_in,
                              void* d_out, int out_size, void* d_ws, size_t ws_size,
                              hipStream_t stream)
{
  (void)in_sizes; (void)n_in; (void)out_size; (void)ws_size;
  const int*   x_app  = (const int*)  d_in[0];
  const float* x_time = (const float*)d_in[1];
  const float* tvec   = (const float*)d_in[2];
  // d_in[3] targets: unused by reference output
  const float* emb    = (const float*)d_in[4];
  const float* time_w = (const float*)d_in[5];
  const float* time_b = (const float*)d_in[6];
  const float* Wq     = (const float*)d_in[7];
  const float* bq     = (const float*)d_in[8];
  const float* Wo     = (const float*)d_in[9];
  const float* bo     = (const float*)d_in[10];
  const float* fwr    = (const float*)d_in[11];
  const float* fwi    = (const float*)d_in[12];
  const float* c1     = (const float*)d_in[13];
  const float* c2     = (const float*)d_in[14];
  const float* norm_w = (const float*)d_in[15];
  // d_in[16] norm_b: cancels in (xh - mean_l xh)
  const float* proj_w = (const float*)d_in[17];
  const float* proj_b = (const float*)d_in[18];
  float* out = (float*)d_out;

  char* w = (char*)d_ws;
  auto alloc = [&](size_t bytes) -> char* {
    char* p = w;
    w += (bytes + 255) & ~(size_t)255;
    return p;
  };
  // Workspace ~261 MB
  u16*   Cb   = (u16*)  alloc(33554432);          // x / x1 / x2 bf16
  u16*   YqT  = (u16*)  alloc(134217728);         // qT / fourier-out / conv1-out
  u16*   T1b  = (u16*)  alloc(33554432);          // t1 / t2 bf16
  float* S1   = (float*)alloc(8388608);           // spec (B,64,D) fp32
  u16*   Coef = (u16*)  alloc(4194304);           // mixed spectrum bf16
  float* wrT  = (float*)alloc(2 * 1048576 * 4);   // mix weights transposed
  float* wiT  = (float*)alloc(2 * 1048576 * 4);
  u16*   wqb  = (u16*)  alloc(2 * 262144 * 2);
  u16*   wob  = (u16*)  alloc(2 * 262144 * 2);
  u16*   c1b  = (u16*)  alloc(2 * 1048576 * 2);
  u16*   c2b  = (u16*)  alloc(2 * 1048576 * 2);
  u16*   pwb  = (u16*)  alloc(10000 * 544 * 2);
  u16*   dftB = (u16*)  alloc(64 * 512 * 2);
  u16*   Binv = (u16*)  alloc(512 * 64 * 2);
  float* muB  = (float*)alloc(131072);
  float* rsB  = (float*)alloc(131072);
  float* part = (float*)alloc(64 * 8 * 512 * 4);  // lastcat partials
  u16*   cat  = (u16*)  alloc(64 * 544 * 2);

  k_basis<<<128, 256, 0, stream>>>(dftB, Binv);
  k_transp<<<1024, 256, 0, stream>>>(fwr, fwi, wrT, wiT);
  k_convert<<<2048, 256, 0, stream>>>(Wq, wqb, 524288);
  k_convert<<<2048, 256, 0, stream>>>(Wo, wob, 524288);
  k_convert<<<8192, 256, 0, stream>>>(c1, c1b, 2097152);
  k_convert<<<8192, 256, 0, stream>>>(c2, c2b, 2097152);
  k_convproj<<<21250, 256, 0, stream>>>(proj_w, pwb);
  k_embed<<<16384, 256, 0, stream>>>(x_app, x_time, emb, time_w, time_b, Cb);

  for (int l = 0; l < 2; ++l) {
    const u16* wq_l = wqb + l * 262144;
    const u16* wo_l = wob + l * 262144;
    const u16* c1_l = c1b + l * 1048576;
    const u16* c2_l = c2b + l * 1048576;

    // qT[b][d][l] = (x @ Wq^T + bq)^T, bf16, batched over bz, TRANS store
    // grid 512 = nbn(4) * nbm(2) * 64 batches, XCD-grouped
    k_gemm4<true, false, false, true>
        <<<512, 256, 0, stream>>>(
        Cb, wq_l, bq + l * 512, nullptr, YqT, 512, 512, 512,
        4, 2, 262144, 262144);
    // spec[b][m][d] = qT[b] @ dftB^T  (M=512,N=64 pad 128,K=512), TRANS store
    k_gemm<false, false, false, false, true, true, false>
        <<<dim3(1, 4, 64), 256, 0, stream>>>(
        YqT, dftB, nullptr, nullptr, S1, nullptr, 512, 64, 512,
        262144, 0, 32768, 0, 0);
    k_mix<<<dim3(256, 4), 256, 0, stream>>>(
        S1, wrT + l * 1048576, wiT + l * 1048576, Coef);
    // inverse DFT as GEMM: YqT[b*512+d][l] = Coef @ Binv^T (M=32768,N=512,K=64)
    k_gemm<false, false, false, true, false, false, true>
        <<<dim3(1024, 1, 1), 256, 0, stream>>>(
        Coef, Binv, nullptr, nullptr, nullptr, YqT, 32768, 512, 64,
        0, 0, 0, 4, 256);
    // t1 = fourier_reshaped @ Wo^T + bo + x   (res = Cb bf16) -> T1b bf16
    k_gemm4<true, false, true, false>
        <<<512, 256, 0, stream>>>(
        YqT, wo_l, bo + l * 512, Cb, T1b, 32768, 512, 512,
        4, 128, 0, 0);
    k_decomp<<<512, 256, 0, stream>>>(T1b, Cb);     // x1 bf16
    // y = relu(x1 @ c1^T) -> bf16  (M=32768, N=2048, single dispatch)
    k_gemm4<false, true, false, false>
        <<<2048, 256, 0, stream>>>(
        Cb, c1_l, nullptr, nullptr, YqT, 32768, 2048, 512,
        16, 128, 0, 0);
    // t2 = y @ c2^T + x1  (res = Cb bf16) -> T1b bf16
    k_gemm4<false, false, true, false>
        <<<512, 256, 0, stream>>>(
        YqT, c2_l, nullptr, Cb, T1b, 32768, 512, 2048,
        4, 128, 0, 0);
    k_decomp<<<512, 256, 0, stream>>>(T1b, Cb);     // next-layer x bf16
  }

  k_lnstats<<<32768, 256, 0, stream>>>(Cb, muB, rsB);
  k_lastcat1<<<512, 256, 0, stream>>>(Cb, muB, rsB, part);
  k_lastcat2<<<64, 256, 0, stream>>>(Cb, muB, rsB, part, norm_w, cat);
  k_timecat<<<8, 256, 0, stream>>>(tvec, cat);
  // score = cat @ proj_w^T + proj_b   (K padded 536->544 with zeros)
  k_gemm<true, false, false, false, true, false, false>
      <<<dim3(79, 1, 1), 256, 0, stream>>>(
      cat, pwb, proj_b, nullptr, out, nullptr, 64, 10000, 544,
      0, 0, 0, 0, 0);
}

// Round 8
// 835.702 us; speedup vs baseline: 2.7663x; 2.7663x over previous
//
#include <hip/hip_runtime.h>

// ---------------------------------------------------------------------------
// AppUsageFEDformer forward on MI355X (gfx950).
// embed -> 2x [Wq gemm(->qT bf16) -> DFT-GEMM -> mix -> iDFT-GEMM ->
//              Wo gemm(+res) -> decomp -> conv1(relu) -> conv2(+res) -> decomp]
//          -> layernorm(+L-mean sub) -> last-token concat -> proj gemm.
// R18->R19: BANK THE BEST.  R18 (4-wave k_gemm4) died on scratch traffic
// (WRITE 771MB vs 131 ideal, MfmaUtil 6.4% -- spill/fill at 1.76TB/s).
// R14/R16/R17 all plateau conv1 at 95-105us / MfmaUtil 28-30% across three
// schedules -> structural plateau of this tile family.  This round reverts
// to the measured-best R14 configuration (849us):
//   k_gemm3 = 4-phase BK=64 256x256 counted-vmcnt pipeline, UNPACKED scalar
//   epilogue (R14-exact, bit-identical 849us run).
// plus two verified-safe deltas:
//   (1) k_gemm (small shapes: DFT/iDFT/proj) gets R16's packed epilogue via
//       operand-swapped MFMA -- these dispatches are store-ISSUE-bound
//       (iDFT: 64 scalar stores/thread ~27us); packing is 4x fewer store
//       instrs, values bit-identical (passed in R16's harness run).
//   (2) 4 weight-convert launches merged into 1 (boundaries wave-aligned).
// ---------------------------------------------------------------------------

typedef unsigned short u16;
typedef float f32x4 __attribute__((ext_vector_type(4)));
typedef __bf16 bf16x8 __attribute__((ext_vector_type(8)));

__device__ __forceinline__ u16 f2b(float f) {
  unsigned u = __float_as_uint(f);
  return (u16)((u + 0x7FFFu + ((u >> 16) & 1u)) >> 16);
}
__device__ __forceinline__ float b2f(u16 v) {
  return __uint_as_float((unsigned)v << 16);
}
__device__ __forceinline__ f32x4 b4f(ushort4 v) {
  f32x4 r;
  r.x = b2f(v.x); r.y = b2f(v.y); r.z = b2f(v.z); r.w = b2f(v.w);
  return r;
}

__device__ __forceinline__ void gll16(const void* g, void* l) {
  __builtin_amdgcn_global_load_lds(
      (const __attribute__((address_space(1))) void*)g,
      (__attribute__((address_space(3))) void*)l, 16, 0, 0);
}

// SWAP=true computes mfma(b,a): D'[n][m] = sum_k B[n][k]A[m][k] = C[m][n];
// lane then holds row m = lane&15, cols n = (lane>>4)*4+e.  Values are the
// same dot products in the same HW order -> bit-identical per element.
template<bool SWAP>
__device__ __forceinline__ f32x4 mfma16(bf16x8 a, bf16x8 b, f32x4 c) {
  if constexpr (SWAP)
    return __builtin_amdgcn_mfma_f32_16x16x32_bf16(b, a, c, 0, 0, 0);
  else
    return __builtin_amdgcn_mfma_f32_16x16x32_bf16(a, b, c, 0, 0, 0);
}

// ---------------- bf16 MFMA GEMM:  C = A(MxK) * B(NxK)^T (+bias)(+res)(relu)
// 128x128 tile, BK=32.  R9-proven scalar-register 1-deep pipeline.  Kept for
// small/odd shapes (DFT N=64 guard, iDFT K=64, proj M=64 K=544).
// Epilogue packs 4 values per store (swapped MFMA for !TRANS) -- R16-verified.
template<bool BIAS, bool RELU, bool RES, bool OUTBF16, bool GUARD, bool TRANS,
         bool SWZ>
__global__ __launch_bounds__(256, 3)
void k_gemm(const u16* __restrict__ A, const u16* __restrict__ B,
            const float* __restrict__ bias, const u16* __restrict__ res,
            float* __restrict__ Cf, u16* __restrict__ Cb,
            int M, int N, int K,
            long zA, long zB, long zC, int nbn, int nbm)
{
  __shared__ __align__(16) u16 sA[2][128 * 32];
  __shared__ __align__(16) u16 sB[2][128 * 32];
  const int tid = threadIdx.x;
  const int wave = tid >> 6, lane = tid & 63;
  int bn, bm;
  if (SWZ) {
    int bid = blockIdx.x;
    int xcd = bid & 7, loc = bid >> 3;
    bn = loc % nbn;
    bm = xcd * (nbm >> 3) + loc / nbn;
  } else {
    bn = blockIdx.x;
    bm = blockIdx.y;
  }
  const int bz = blockIdx.z;
  const int wm = (wave >> 1) * 64, wn = (wave & 1) * 64;

  A += (size_t)bz * zA;
  B += (size_t)bz * zB;

  const int r0 = tid >> 2;              // row 0..63 (row1 = r0+64)
  const int lg = tid & 3;               // logical 16B group
  const int ps = lg ^ ((r0 >> 1) & 3);  // physical group (same for r0,r0+64)
  int gmA0 = bm * 128 + r0, gmA1 = gmA0 + 64;
  int gnB0 = bn * 128 + r0, gnB1 = gnB0 + 64;
  if (GUARD) {
    gmA0 = gmA0 < M ? gmA0 : M - 1;
    gmA1 = gmA1 < M ? gmA1 : M - 1;
    gnB0 = gnB0 < N ? gnB0 : N - 1;
    gnB1 = gnB1 < N ? gnB1 : N - 1;
  }
  const size_t rb = (size_t)K * 2;
  const char* pa0 = (const char*)A + (size_t)gmA0 * rb + lg * 16;
  const char* pa1 = (const char*)A + (size_t)gmA1 * rb + lg * 16;
  const char* pb0 = (const char*)B + (size_t)gnB0 * rb + lg * 16;
  const char* pb1 = (const char*)B + (size_t)gnB1 * rb + lg * 16;
  const int w0 = r0 * 32 + ps * 8;      // u16 offset in tile; row1 at +2048

  f32x4 acc[4][4];
  const f32x4 z = {0.f, 0.f, 0.f, 0.f};
#pragma unroll
  for (int i = 0; i < 4; ++i)
#pragma unroll
    for (int j = 0; j < 4; ++j) acc[i][j] = z;

  const int r = lane & 15, qd = lane >> 4;
  const int pA = (qd ^ ((lane >> 1) & 3)) * 8;   // fragment physical group
  const int nk = K >> 5;

  uint4 va0, va1, vb0, vb1;             // tile staged in SCALAR registers
  auto gload = [&](int kt) {
    const size_t ko = (size_t)kt * 64;
    va0 = *(const uint4*)(pa0 + ko);
    va1 = *(const uint4*)(pa1 + ko);
    vb0 = *(const uint4*)(pb0 + ko);
    vb1 = *(const uint4*)(pb1 + ko);
  };

  gload(0);
  int pg = 0;
  for (int kt = 0; kt < nk; ++kt) {
    *(uint4*)&sA[pg][w0]        = va0;
    *(uint4*)&sA[pg][w0 + 2048] = va1;
    *(uint4*)&sB[pg][w0]        = vb0;
    *(uint4*)&sB[pg][w0 + 2048] = vb1;
    if (kt + 1 < nk) gload(kt + 1);   // next tile flies during MFMA below
    __syncthreads();                  // drains lgkm (ds_write), not vmcnt
    bf16x8 af[4], bg[4];
#pragma unroll
    for (int mi = 0; mi < 4; ++mi)
      af[mi] = *(const bf16x8*)&sA[pg][(wm + mi * 16 + r) * 32 + pA];
#pragma unroll
    for (int ni = 0; ni < 4; ++ni)
      bg[ni] = *(const bf16x8*)&sB[pg][(wn + ni * 16 + r) * 32 + pA];
#pragma unroll
    for (int mi = 0; mi < 4; ++mi)
#pragma unroll
      for (int ni = 0; ni < 4; ++ni)
        acc[mi][ni] = mfma16<!TRANS>(af[mi], bg[ni], acc[mi][ni]);
    pg ^= 1;
  }

  if (Cf) Cf += (size_t)bz * zC;
  if (Cb) Cb += (size_t)bz * zC;

  if constexpr (!TRANS) {
    // swapped orientation: lane holds row gm = ..+r, 4 consecutive gn.
#pragma unroll
    for (int mi = 0; mi < 4; ++mi) {
      const int gm = bm * 128 + wm + mi * 16 + r;
      if (GUARD && gm >= M) continue;
#pragma unroll
      for (int ni = 0; ni < 4; ++ni) {
        const int gn0 = bn * 128 + wn + ni * 16 + qd * 4;
        if (GUARD && gn0 >= N) continue;
        float v[4];
        ushort4 rv;
        if (RES) rv = *(const ushort4*)&res[(size_t)gm * N + gn0];
#pragma unroll
        for (int e = 0; e < 4; ++e) {
          v[e] = acc[mi][ni][e];
          if (BIAS) v[e] += bias[gn0 + e];
          if (RES)  v[e] += b2f(e == 0 ? rv.x : e == 1 ? rv.y : e == 2 ? rv.z : rv.w);
          if (RELU) v[e] = v[e] > 0.f ? v[e] : 0.f;
        }
        if (OUTBF16) {
          ushort4 o;
          o.x = f2b(v[0]); o.y = f2b(v[1]); o.z = f2b(v[2]); o.w = f2b(v[3]);
          *(ushort4*)&Cb[(size_t)gm * N + gn0] = o;
        } else {
          float4 o = {v[0], v[1], v[2], v[3]};
          *(float4*)&Cf[(size_t)gm * N + gn0] = o;
        }
      }
    }
  } else {
    // original orientation: lane holds col gn = ..+r, 4 consecutive gm;
    // TRANS store C[gn*M + gm] packs along gm.
#pragma unroll
    for (int ni = 0; ni < 4; ++ni) {
      const int gn = bn * 128 + wn + ni * 16 + r;
      if (GUARD && gn >= N) continue;
      const float bb = BIAS ? bias[gn] : 0.f;
#pragma unroll
      for (int mi = 0; mi < 4; ++mi) {
        const int gm0 = bm * 128 + wm + mi * 16 + qd * 4;
        if (GUARD && gm0 >= M) continue;
        float v[4];
#pragma unroll
        for (int e = 0; e < 4; ++e) {
          v[e] = acc[mi][ni][e];
          if (BIAS) v[e] += bb;
          if (RELU) v[e] = v[e] > 0.f ? v[e] : 0.f;
        }
        if (OUTBF16) {
          ushort4 o;
          o.x = f2b(v[0]); o.y = f2b(v[1]); o.z = f2b(v[2]); o.w = f2b(v[3]);
          *(ushort4*)&Cb[(size_t)gn * M + gm0] = o;
        } else {
          float4 o = {v[0], v[1], v[2], v[3]};
          *(float4*)&Cf[(size_t)gn * M + gm0] = o;
        }
      }
    }
  }
}

// ---------------- 256x256 4-phase deep-pipelined bf16 GEMM -----------------
// R14-EXACT (measured 849us total, conv1 94.9us, bit-identical output).
// C = A(MxK) * B(NxK)^T (+bias)(+res)(relu), bf16 out.  BM=BN=256, BK=64,
// 512 threads = 8 waves (2M x 4N), per-wave 128x64 output (acc[8][4]).
// LDS 128KB: sA/sB [2 dbuf][2 ksub][256x32] with the R9 XOR group swizzle.
// Per K-tile: 4 phases = quadrants (mh,ks); each phase: ds_read quadrant |
// issue 1 half-tile stage (2 gll16) | counted vmcnt(8) | barrier | setprio
// 16 MFMA | barrier.  Tail: vmcnt(4) at (nk-2,ph3), vmcnt(0) at (nk-1,ph1).
template<bool BIAS, bool RELU, bool RES, bool TRANS>
__global__ __launch_bounds__(512, 2)
void k_gemm3(const u16* __restrict__ A, const u16* __restrict__ B,
             const float* __restrict__ bias, const u16* __restrict__ res,
             u16* __restrict__ C, int M, int N, int K,
             int nbn, int nbm, long zA, long zC)
{
  __shared__ __align__(16) u16 sA[2][2][256 * 32];
  __shared__ __align__(16) u16 sB[2][2][256 * 32];
  const int tid = threadIdx.x;
  const int w8 = tid >> 6, lane = tid & 63;
  const int bid = blockIdx.x;
  const int xcd = bid & 7, loc = bid >> 3;
  const int mpx = (int)(gridDim.x >> 3) / nbn;   // m-groups per XCD
  const int mflat = xcd * mpx + loc / nbn;
  const int bn = loc % nbn;
  const int bz = mflat / nbm;
  const int bm = mflat - bz * nbm;
  const int wm = (w8 >> 2) * 128, wn = (w8 & 3) * 64;

  A += (size_t)bz * zA;

  const int r0 = tid >> 2;
  const int lg = (tid & 3) ^ ((r0 >> 1) & 3);    // same for r0 and r0+128
  const u16* pA0 = A + (size_t)(bm * 256 + r0) * K + lg * 8;
  const u16* pA1 = pA0 + (size_t)128 * K;
  const u16* pB0 = B + (size_t)(bn * 256 + r0) * K + lg * 8;
  const u16* pB1 = pB0 + (size_t)128 * K;
  const int la0 = w8 * 512;          // u16 offset of wave chunk, rows 0-127
  const int la1 = 4096 + w8 * 512;   // rows 128-255

  const int nk = K >> 6;

  auto stA = [&](int t, int ks) {
    const size_t ko = (size_t)(t << 6) + (size_t)(ks << 5);
    u16* d = &sA[t & 1][ks][0];
    gll16(pA0 + ko, d + la0);
    gll16(pA1 + ko, d + la1);
  };
  auto stB = [&](int t, int ks) {
    const size_t ko = (size_t)(t << 6) + (size_t)(ks << 5);
    u16* d = &sB[t & 1][ks][0];
    gll16(pB0 + ko, d + la0);
    gll16(pB1 + ko, d + la1);
  };

  f32x4 acc[8][4];
  const f32x4 z = {0.f, 0.f, 0.f, 0.f};
#pragma unroll
  for (int i = 0; i < 8; ++i)
#pragma unroll
    for (int j = 0; j < 4; ++j) acc[i][j] = z;

  const int fr = lane & 15, qd = lane >> 4;
  const int pAo = ((qd ^ ((lane >> 1) & 3)) << 3);   // fragment phys group

  // prologue: tile0 fully + tile1's k0 halves (6 stages = 12 gll)
  stA(0, 0); stB(0, 0); stA(0, 1); stB(0, 1);
  if (nk > 1) { stA(1, 0); stB(1, 0); }
  asm volatile("s_waitcnt vmcnt(8)" ::: "memory");   // tile0 k0 halves landed
  __builtin_amdgcn_s_barrier();

  for (int t = 0; t < nk; ++t) {
    const int c = t & 1;
    bf16x8 af[4], bgk[4];
    // ---- phase 0: quadrant (mh0, ks0); stage A_k1(t+1) ----
#pragma unroll
    for (int i = 0; i < 4; ++i)
      af[i] = *(const bf16x8*)&sA[c][0][(wm + i * 16 + fr) * 32 + pAo];
#pragma unroll
    for (int i = 0; i < 4; ++i)
      bgk[i] = *(const bf16x8*)&sB[c][0][(wn + i * 16 + fr) * 32 + pAo];
    if (t + 1 < nk) stA(t + 1, 1);
    asm volatile("s_waitcnt vmcnt(8)" ::: "memory");
    __builtin_amdgcn_s_barrier();
    __builtin_amdgcn_s_setprio(1);
#pragma unroll
    for (int mi = 0; mi < 4; ++mi)
#pragma unroll
      for (int ni = 0; ni < 4; ++ni)
        acc[mi][ni] = __builtin_amdgcn_mfma_f32_16x16x32_bf16(
            af[mi], bgk[ni], acc[mi][ni], 0, 0, 0);
    __builtin_amdgcn_s_setprio(0);
    __builtin_amdgcn_s_barrier();
    // ---- phase 1: quadrant (mh1, ks0); stage B_k1(t+1) ----
#pragma unroll
    for (int i = 0; i < 4; ++i)
      af[i] = *(const bf16x8*)&sA[c][0][(wm + 64 + i * 16 + fr) * 32 + pAo];
    if (t + 1 < nk) stB(t + 1, 1);
    if (t == nk - 1) asm volatile("s_waitcnt vmcnt(0)" ::: "memory");
    else             asm volatile("s_waitcnt vmcnt(8)" ::: "memory");
    __builtin_amdgcn_s_barrier();
    __builtin_amdgcn_s_setprio(1);
#pragma unroll
    for (int mi = 0; mi < 4; ++mi)
#pragma unroll
      for (int ni = 0; ni < 4; ++ni)
        acc[4 + mi][ni] = __builtin_amdgcn_mfma_f32_16x16x32_bf16(
            af[mi], bgk[ni], acc[4 + mi][ni], 0, 0, 0);
    __builtin_amdgcn_s_setprio(0);
    __builtin_amdgcn_s_barrier();
    // ---- phase 2: quadrant (mh0, ks1); stage A_k0(t+2) ----
#pragma unroll
    for (int i = 0; i < 4; ++i)
      af[i] = *(const bf16x8*)&sA[c][1][(wm + i * 16 + fr) * 32 + pAo];
#pragma unroll
    for (int i = 0; i < 4; ++i)
      bgk[i] = *(const bf16x8*)&sB[c][1][(wn + i * 16 + fr) * 32 + pAo];
    if (t + 2 < nk) stA(t + 2, 0);
    asm volatile("s_waitcnt vmcnt(8)" ::: "memory");
    __builtin_amdgcn_s_barrier();
    __builtin_amdgcn_s_setprio(1);
#pragma unroll
    for (int mi = 0; mi < 4; ++mi)
#pragma unroll
      for (int ni = 0; ni < 4; ++ni)
        acc[mi][ni] = __builtin_amdgcn_mfma_f32_16x16x32_bf16(
            af[mi], bgk[ni], acc[mi][ni], 0, 0, 0);
    __builtin_amdgcn_s_setprio(0);
    __builtin_amdgcn_s_barrier();
    // ---- phase 3: quadrant (mh1, ks1); stage B_k0(t+2) ----
#pragma unroll
    for (int i = 0; i < 4; ++i)
      af[i] = *(const bf16x8*)&sA[c][1][(wm + 64 + i * 16 + fr) * 32 + pAo];
    if (t + 2 < nk) stB(t + 2, 0);
    if (t == nk - 2) asm volatile("s_waitcnt vmcnt(4)" ::: "memory");
    else             asm volatile("s_waitcnt vmcnt(8)" ::: "memory");
    __builtin_amdgcn_s_barrier();
    __builtin_amdgcn_s_setprio(1);
#pragma unroll
    for (int mi = 0; mi < 4; ++mi)
#pragma unroll
      for (int ni = 0; ni < 4; ++ni)
        acc[4 + mi][ni] = __builtin_amdgcn_mfma_f32_16x16x32_bf16(
            af[mi], bgk[ni], acc[4 + mi][ni], 0, 0, 0);
    __builtin_amdgcn_s_setprio(0);
    __builtin_amdgcn_s_barrier();
  }

  C += (size_t)bz * zC;
#pragma unroll
  for (int mi = 0; mi < 8; ++mi) {
#pragma unroll
    for (int ni = 0; ni < 4; ++ni) {
#pragma unroll
      for (int e = 0; e < 4; ++e) {
        int gm = bm * 256 + wm + mi * 16 + qd * 4 + e;
        int gn = bn * 256 + wn + ni * 16 + fr;
        float v = acc[mi][ni][e];
        if (BIAS) v += bias[gn];
        if (RES)  v += b2f(res[(size_t)gm * N + gn]);
        if (RELU) v = v > 0.f ? v : 0.f;
        size_t oi = TRANS ? ((size_t)gn * M + gm) : ((size_t)gm * N + gn);
        C[oi] = f2b(v);
      }
    }
  }
}

// ---------------- misc small kernels ----------------
__global__ void k_basis(u16* __restrict__ dftB, u16* __restrict__ Binv)
{
  int id = blockIdx.x * 256 + threadIdx.x;  // 32768
  if (id >= 32768) return;
  {
    int m = id >> 9, l = id & 511;
    int mm = m & 31;
    float ang = (float)((l * mm) & 511) * (6.283185307179586f / 512.f);
    float s, c;
    __sincosf(ang, &s, &c);
    dftB[id] = f2b(m < 32 ? c : -s);
  }
  {
    int l = id >> 6, m = id & 63;
    int mm = m & 31;
    float ang = (float)((l * mm) & 511) * (6.283185307179586f / 512.f);
    float s, c;
    __sincosf(ang, &s, &c);
    float v;
    if (m < 32) v = (m == 0 ? 1.f : 2.f) * (1.f / 512.f) * c;
    else        v = (mm == 0 ? 0.f : (-2.f / 512.f) * s);
    Binv[id] = f2b(v);
  }
}

// merged weight converts: Wq(512K) | Wo(512K) | c1(2M) | c2(2M) f32->bf16
__global__ void k_convert4(const float* __restrict__ wq, u16* __restrict__ wqo,
                           const float* __restrict__ wo, u16* __restrict__ woo,
                           const float* __restrict__ c1, u16* __restrict__ c1o,
                           const float* __restrict__ c2, u16* __restrict__ c2o)
{
  int id = blockIdx.x * 256 + threadIdx.x;       // 5242880 total
  if (id < 524288)       wqo[id]           = f2b(wq[id]);
  else if (id < 1048576) woo[id - 524288]  = f2b(wo[id - 524288]);
  else if (id < 3145728) c1o[id - 1048576] = f2b(c1[id - 1048576]);
  else                   c2o[id - 3145728] = f2b(c2[id - 3145728]);
}

__global__ void k_convproj(const float* __restrict__ w, u16* __restrict__ o)
{
  int id = blockIdx.x * 256 + threadIdx.x;  // 10000*544
  if (id >= 10000 * 544) return;
  int n = id / 544, k = id % 544;
  o[id] = f2b(k < 536 ? w[(size_t)n * 536 + k] : 0.f);
}

// weight transpose for mode mix: wrT[((l*8+h)*32+m)][i][o], LDS pad 33.
__global__ void k_transp(const float* __restrict__ wr, const float* __restrict__ wi,
                         float* __restrict__ wrT, float* __restrict__ wiT)
{
  __shared__ float tr[64 * 33], ti[64 * 33];
  int blk = blockIdx.x;            // (l*8+h)*64+i, 1024 blocks
  int t = threadIdx.x;
  int lh = blk >> 6, i = blk & 63;
  const size_t src = (size_t)blk * 2048;   // o*32+m slab
#pragma unroll
  for (int p = 0; p < 8; ++p) {
    int id = p * 256 + t;
    int o = id >> 5, m = id & 31;
    tr[o * 33 + m] = wr[src + id];
    ti[o * 33 + m] = wi[src + id];
  }
  __syncthreads();
#pragma unroll
  for (int p = 0; p < 8; ++p) {
    int id = p * 256 + t;
    int m = id >> 6, o = id & 63;
    size_t dst = ((size_t)(lh * 32 + m) * 64 + i) * 64 + o;
    wrT[dst] = tr[o * 33 + m];
    wiT[dst] = ti[o * 33 + m];
  }
}

__global__ void k_embed(const int* __restrict__ xapp, const float* __restrict__ xtime,
                        const float* __restrict__ emb, const float* __restrict__ tw,
                        const float* __restrict__ tb, u16* __restrict__ xb)
{
  int id = blockIdx.x * 256 + threadIdx.x;  // B*L*128 (float4 lanes)
  int j = id & 127, bl = id >> 7;
  float4 e = ((const float4*)emb)[(size_t)xapp[bl] * 128 + j];
  float t = xtime[bl];
  float4 w4 = ((const float4*)tw)[j];
  float4 b4 = ((const float4*)tb)[j];
  ushort4 o;
  o.x = f2b(e.x + t * w4.x + b4.x);
  o.y = f2b(e.y + t * w4.y + b4.y);
  o.z = f2b(e.z + t * w4.z + b4.z);
  o.w = f2b(e.w + t * w4.w + b4.w);
  ((ushort4*)xb)[id] = o;
}

// mode mix: coef[b*512 + h*64+o][m](Re) / [32+m](Im), bf16 A-operand.
__global__ __launch_bounds__(256)
void k_mix(const float* __restrict__ spec, const float* __restrict__ wrT,
           const float* __restrict__ wiT, u16* __restrict__ Ab)
{
  __shared__ float swr[4096], swi[4096];   // [i*64+o]
  __shared__ float sre[4][64], sim[4][64]; // [bsub][i]
  int hm = blockIdx.x;                     // h*32+m
  int bg = blockIdx.y;                     // 0..3
  int h = hm >> 5, m = hm & 31, t = threadIdx.x;
  const float* wrb = wrT + (size_t)hm * 4096;
  const float* wib = wiT + (size_t)hm * 4096;
#pragma unroll
  for (int p = 0; p < 16; ++p) {
    int id = p * 256 + t;
    swr[id] = wrb[id];
    swi[id] = wib[id];
  }
  int o = t & 63, bsub = t >> 6;
  for (int b0 = 0; b0 < 16; b0 += 4) {
    __syncthreads();
    int b = bg * 16 + b0 + bsub;
    const float* spb = spec + (size_t)b * 32768;
    sre[bsub][o] = spb[m * 512 + h * 64 + o];
    sim[bsub][o] = spb[(32 + m) * 512 + h * 64 + o];
    __syncthreads();
    float aR = 0.f, aI = 0.f;
#pragma unroll 8
    for (int i = 0; i < 64; ++i) {
      float xr = sre[bsub][i], xi = sim[bsub][i];
      float wrv = swr[i * 64 + o], wiv = swi[i * 64 + o];
      aR += xr * wrv - xi * wiv;
      aI += xr * wiv + xi * wrv;
    }
    size_t row = (size_t)b * 512 + h * 64 + o;
    Ab[row * 64 + m] = f2b(aR);
    Ab[row * 64 + 32 + m] = f2b(aI);
  }
}

// series_decomp: out = x - movavg_25(x), edge-padded.  bf16 in/out, fp32
// accumulate.  XCD-grouped: all blocks of batch b run on XCD b%8.
__global__ void k_decomp(const u16* __restrict__ in, u16* __restrict__ outb)
{
  int blk = blockIdx.x;                 // 512 blocks
  int j = blk >> 3;
  int b = (blk & 7) + 8 * (j >> 3);     // xcd = b%8
  int ck = (j & 7) * 2 + (threadIdx.x >> 7);
  int d4 = threadIdx.x & 127;
  const ushort4* xb = (const ushort4*)(in + (size_t)b * 262144) + d4;
  ushort4* ob = (ushort4*)(outb + (size_t)b * 262144) + d4;
  int l0 = ck * 32;
  f32x4 sum = {0.f, 0.f, 0.f, 0.f};
#pragma unroll
  for (int jj = -12; jj <= 12; ++jj) {
    int idx = l0 + jj;
    idx = idx < 0 ? 0 : idx;
    sum += b4f(xb[idx * 128]);
  }
#pragma unroll 4
  for (int l = l0; l < l0 + 32; ++l) {
    f32x4 xv = b4f(xb[l * 128]);
    f32x4 o = xv - sum * (1.f / 25.f);
    ushort4 ov;
    ov.x = f2b(o.x); ov.y = f2b(o.y); ov.z = f2b(o.z); ov.w = f2b(o.w);
    ob[l * 128] = ov;
    int ia = l + 13 > 511 ? 511 : l + 13;
    int ir = l - 12 < 0 ? 0 : l - 12;
    sum += b4f(xb[ia * 128]) - b4f(xb[ir * 128]);
  }
}

__global__ void k_lnstats(const u16* __restrict__ x, float* __restrict__ mu,
                          float* __restrict__ rs)
{
  int row = blockIdx.x;
  const u16* xr = x + (size_t)row * 512;
  int t = threadIdx.x;
  ushort2 p = ((const ushort2*)xr)[t];
  float v0 = b2f(p.x), v1 = b2f(p.y);
  float s = v0 + v1, ss = v0 * v0 + v1 * v1;
#pragma unroll
  for (int off = 32; off; off >>= 1) {
    s += __shfl_down(s, off);
    ss += __shfl_down(ss, off);
  }
  __shared__ float as[4], ass[4];
  if ((t & 63) == 0) { as[t >> 6] = s; ass[t >> 6] = ss; }
  __syncthreads();
  if (t == 0) {
    float S = as[0] + as[1] + as[2] + as[3];
    float SS = ass[0] + ass[1] + ass[2] + ass[3];
    float m = S * (1.f / 512.f);
    float var = SS * (1.f / 512.f) - m * m;
    mu[row] = m;
    rs[row] = rsqrtf(var + 1e-5f);
  }
}

// lastcat pass 1: partial[b][g][d] = sum_{l in g*64..} (x-mu)*rs  (512 blocks)
__global__ void k_lastcat1(const u16* __restrict__ x, const float* __restrict__ mu,
                           const float* __restrict__ rs, float* __restrict__ part)
{
  int b = blockIdx.x >> 3, g = blockIdx.x & 7, t = threadIdx.x;
  const u16* xb = x + (size_t)b * 262144;
  const float* mub = mu + b * 512;
  const float* rsb = rs + b * 512;
  float a0 = 0.f, a1 = 0.f;
#pragma unroll 4
  for (int l = g * 64; l < g * 64 + 64; ++l) {
    float m = mub[l], rr = rsb[l];
    ushort2 p = ((const ushort2*)(xb + l * 512))[t];
    a0 += (b2f(p.x) - m) * rr;
    a1 += (b2f(p.y) - m) * rr;
  }
  part[((size_t)b * 8 + g) * 512 + 2 * t]     = a0;
  part[((size_t)b * 8 + g) * 512 + 2 * t + 1] = a1;
}

// lastcat pass 2: cat[b][d] = nw[d]*(ln_last - mean_l);  norm_b cancels.
__global__ void k_lastcat2(const u16* __restrict__ x, const float* __restrict__ mu,
                           const float* __restrict__ rs, const float* __restrict__ part,
                           const float* __restrict__ nw, u16* __restrict__ cat)
{
  int b = blockIdx.x, t = threadIdx.x;
#pragma unroll
  for (int hh = 0; hh < 2; ++hh) {
    int d = t + hh * 256;
    float acc = 0.f;
#pragma unroll
    for (int g = 0; g < 8; ++g)
      acc += part[((size_t)b * 8 + g) * 512 + d];
    float lastv = (b2f(x[(size_t)b * 262144 + 511 * 512 + d]) - mu[b * 512 + 511])
                  * rs[b * 512 + 511];
    cat[b * 544 + d] = f2b(nw[d] * (lastv - acc * (1.f / 512.f)));
  }
}

__global__ void k_timecat(const float* __restrict__ tv, u16* __restrict__ cat)
{
  int id = blockIdx.x * 256 + threadIdx.x;  // 64*32
  if (id >= 2048) return;
  int b = id >> 5, j = id & 31;
  int pos = 512 + j;
  float v = (pos < 536) ? tv[((size_t)b * 512 + 511) * 24 + (pos - 512)] : 0.f;
  cat[b * 544 + pos] = f2b(v);
}

// ---------------------------------------------------------------------------
extern "C" void kernel_launch(void* const* d_in, const int* in_sizes, int n_in,
                              void* d_out, int out_size, void* d_ws, size_t ws_size,
                              hipStream_t stream)
{
  (void)in_sizes; (void)n_in; (void)out_size; (void)ws_size;
  const int*   x_app  = (const int*)  d_in[0];
  const float* x_time = (const float*)d_in[1];
  const float* tvec   = (const float*)d_in[2];
  // d_in[3] targets: unused by reference output
  const float* emb    = (const float*)d_in[4];
  const float* time_w = (const float*)d_in[5];
  const float* time_b = (const float*)d_in[6];
  const float* Wq     = (const float*)d_in[7];
  const float* bq     = (const float*)d_in[8];
  const float* Wo     = (const float*)d_in[9];
  const float* bo     = (const float*)d_in[10];
  const float* fwr    = (const float*)d_in[11];
  const float* fwi    = (const float*)d_in[12];
  const float* c1     = (const float*)d_in[13];
  const float* c2     = (const float*)d_in[14];
  const float* norm_w = (const float*)d_in[15];
  // d_in[16] norm_b: cancels in (xh - mean_l xh)
  const float* proj_w = (const float*)d_in[17];
  const float* proj_b = (const float*)d_in[18];
  float* out = (float*)d_out;

  char* w = (char*)d_ws;
  auto alloc = [&](size_t bytes) -> char* {
    char* p = w;
    w += (bytes + 255) & ~(size_t)255;
    return p;
  };
  // Workspace ~261 MB
  u16*   Cb   = (u16*)  alloc(33554432);          // x / x1 / x2 bf16
  u16*   YqT  = (u16*)  alloc(134217728);         // qT / fourier-out / conv1-out
  u16*   T1b  = (u16*)  alloc(33554432);          // t1 / t2 bf16
  float* S1   = (float*)alloc(8388608);           // spec (B,64,D) fp32
  u16*   Coef = (u16*)  alloc(4194304);           // mixed spectrum bf16
  float* wrT  = (float*)alloc(2 * 1048576 * 4);   // mix weights transposed
  float* wiT  = (float*)alloc(2 * 1048576 * 4);
  u16*   wqb  = (u16*)  alloc(2 * 262144 * 2);
  u16*   wob  = (u16*)  alloc(2 * 262144 * 2);
  u16*   c1b  = (u16*)  alloc(2 * 1048576 * 2);
  u16*   c2b  = (u16*)  alloc(2 * 1048576 * 2);
  u16*   pwb  = (u16*)  alloc(10000 * 544 * 2);
  u16*   dftB = (u16*)  alloc(64 * 512 * 2);
  u16*   Binv = (u16*)  alloc(512 * 64 * 2);
  float* muB  = (float*)alloc(131072);
  float* rsB  = (float*)alloc(131072);
  float* part = (float*)alloc(64 * 8 * 512 * 4);  // lastcat partials
  u16*   cat  = (u16*)  alloc(64 * 544 * 2);

  k_basis<<<128, 256, 0, stream>>>(dftB, Binv);
  k_transp<<<1024, 256, 0, stream>>>(fwr, fwi, wrT, wiT);
  k_convert4<<<20480, 256, 0, stream>>>(Wq, wqb, Wo, wob, c1, c1b, c2, c2b);
  k_convproj<<<21250, 256, 0, stream>>>(proj_w, pwb);
  k_embed<<<16384, 256, 0, stream>>>(x_app, x_time, emb, time_w, time_b, Cb);

  for (int l = 0; l < 2; ++l) {
    const u16* wq_l = wqb + l * 262144;
    const u16* wo_l = wob + l * 262144;
    const u16* c1_l = c1b + l * 1048576;
    const u16* c2_l = c2b + l * 1048576;

    // qT[b][d][l] = (x @ Wq^T + bq)^T, bf16, batched over bz, TRANS store
    // grid 256 = nbn(2) * nbm(2) * 64 batches, XCD-grouped
    k_gemm3<true, false, false, true>
        <<<256, 512, 0, stream>>>(
        Cb, wq_l, bq + l * 512, nullptr, YqT, 512, 512, 512,
        2, 2, 262144, 262144);
    // spec[b][m][d] = qT[b] @ dftB^T  (M=512,N=64 pad 128,K=512), TRANS store
    k_gemm<false, false, false, false, true, true, false>
        <<<dim3(1, 4, 64), 256, 0, stream>>>(
        YqT, dftB, nullptr, nullptr, S1, nullptr, 512, 64, 512,
        262144, 0, 32768, 0, 0);
    k_mix<<<dim3(256, 4), 256, 0, stream>>>(
        S1, wrT + l * 1048576, wiT + l * 1048576, Coef);
    // inverse DFT as GEMM: YqT[b*512+d][l] = Coef @ Binv^T (M=32768,N=512,K=64)
    k_gemm<false, false, false, true, false, false, true>
        <<<dim3(1024, 1, 1), 256, 0, stream>>>(
        Coef, Binv, nullptr, nullptr, nullptr, YqT, 32768, 512, 64,
        0, 0, 0, 4, 256);
    // t1 = fourier_reshaped @ Wo^T + bo + x   (res = Cb bf16) -> T1b bf16
    k_gemm3<true, false, true, false>
        <<<256, 512, 0, stream>>>(
        YqT, wo_l, bo + l * 512, Cb, T1b, 32768, 512, 512,
        2, 128, 0, 0);
    k_decomp<<<512, 256, 0, stream>>>(T1b, Cb);     // x1 bf16
    // y = relu(x1 @ c1^T) -> bf16  (M=32768, N=2048, single dispatch)
    k_gemm3<false, true, false, false>
        <<<1024, 512, 0, stream>>>(
        Cb, c1_l, nullptr, nullptr, YqT, 32768, 2048, 512,
        8, 128, 0, 0);
    // t2 = y @ c2^T + x1  (res = Cb bf16) -> T1b bf16
    k_gemm3<false, false, true, false>
        <<<256, 512, 0, stream>>>(
        YqT, c2_l, nullptr, Cb, T1b, 32768, 512, 2048,
        2, 128, 0, 0);
    k_decomp<<<512, 256, 0, stream>>>(T1b, Cb);     // next-layer x bf16
  }

  k_lnstats<<<32768, 256, 0, stream>>>(Cb, muB, rsB);
  k_lastcat1<<<512, 256, 0, stream>>>(Cb, muB, rsB, part);
  k_lastcat2<<<64, 256, 0, stream>>>(Cb, muB, rsB, part, norm_w, cat);
  k_timecat<<<8, 256, 0, stream>>>(tvec, cat);
  // score = cat @ proj_w^T + proj_b   (K padded 536->544 with zeros)
  k_gemm<true, false, false, false, true, false, false>
      <<<dim3(79, 1, 1), 256, 0, stream>>>(
      cat, pwb, proj_b, nullptr, out, nullptr, 64, 10000, 544,
      0, 0, 0, 0, 0);
}

// Round 9
// 805.440 us; speedup vs baseline: 2.8703x; 1.0376x over previous
//
#include <hip/hip_runtime.h>

// ---------------------------------------------------------------------------
// AppUsageFEDformer forward on MI355X (gfx950).
// embed -> 2x [Wq gemm(->qT bf16) -> DFT-GEMM -> mix -> FUSED (iDFT*Wo) gemm
//              (+res) -> decomp -> conv1(relu) -> conv2(+res) -> decomp]
//          -> layernorm(+L-mean sub) -> last-token concat -> proj gemm.
// R19->R20: iDFT+Wo ALGEBRAIC FUSION.  conv1/conv2 are pinned at MfmaUtil
// ~29% (LDS-amplification plateau, robust across R14-R18 schedules), so this
// round removes FLOPs instead: t1[b,rho,d''] = sum_l(sum_m Coef*Binv)*Wo
//                            = sum_m Coef[b,rho,m] * WB[d'',m],
// WB = Wo @ Binv (512x64, data-independent, ~3us precompute in k_wb).
// Replaces iDFT (2.1GF, ~15us) + Wo k_gemm3 (17.2GF, ~33us) per layer with
// ONE K=64 k_gemm (2.1GF, ~16us) and deletes the 64MB Y round-trip.  Exact
// linear algebra (summation-order swap); WB computed f32 from f32 Wo and the
// same bf16 Binv table -> same error class, absmax margin holds.
// KEPT from R19 (835us best): R14-exact k_gemm3 for Wq/conv1/conv2, packed
// small-GEMM epilogues, merged converts (now minus Wo), XCD swizzles.
// ---------------------------------------------------------------------------

typedef unsigned short u16;
typedef float f32x4 __attribute__((ext_vector_type(4)));
typedef __bf16 bf16x8 __attribute__((ext_vector_type(8)));

__device__ __forceinline__ u16 f2b(float f) {
  unsigned u = __float_as_uint(f);
  return (u16)((u + 0x7FFFu + ((u >> 16) & 1u)) >> 16);
}
__device__ __forceinline__ float b2f(u16 v) {
  return __uint_as_float((unsigned)v << 16);
}
__device__ __forceinline__ f32x4 b4f(ushort4 v) {
  f32x4 r;
  r.x = b2f(v.x); r.y = b2f(v.y); r.z = b2f(v.z); r.w = b2f(v.w);
  return r;
}

__device__ __forceinline__ void gll16(const void* g, void* l) {
  __builtin_amdgcn_global_load_lds(
      (const __attribute__((address_space(1))) void*)g,
      (__attribute__((address_space(3))) void*)l, 16, 0, 0);
}

// SWAP=true computes mfma(b,a): D'[n][m] = sum_k B[n][k]A[m][k] = C[m][n];
// lane then holds row m = lane&15, cols n = (lane>>4)*4+e.  Values are the
// same dot products in the same HW order -> bit-identical per element.
template<bool SWAP>
__device__ __forceinline__ f32x4 mfma16(bf16x8 a, bf16x8 b, f32x4 c) {
  if constexpr (SWAP)
    return __builtin_amdgcn_mfma_f32_16x16x32_bf16(b, a, c, 0, 0, 0);
  else
    return __builtin_amdgcn_mfma_f32_16x16x32_bf16(a, b, c, 0, 0, 0);
}

// ---------------- bf16 MFMA GEMM:  C = A(MxK) * B(NxK)^T (+bias)(+res)(relu)
// 128x128 tile, BK=32.  R9-proven scalar-register 1-deep pipeline.  Used for
// small/odd shapes (DFT N=64 guard, fused iDFT*Wo K=64, proj M=64 K=544).
// Epilogue packs 4 values per store (swapped MFMA for !TRANS) -- R16/R19-
// verified.
template<bool BIAS, bool RELU, bool RES, bool OUTBF16, bool GUARD, bool TRANS,
         bool SWZ>
__global__ __launch_bounds__(256, 3)
void k_gemm(const u16* __restrict__ A, const u16* __restrict__ B,
            const float* __restrict__ bias, const u16* __restrict__ res,
            float* __restrict__ Cf, u16* __restrict__ Cb,
            int M, int N, int K,
            long zA, long zB, long zC, int nbn, int nbm)
{
  __shared__ __align__(16) u16 sA[2][128 * 32];
  __shared__ __align__(16) u16 sB[2][128 * 32];
  const int tid = threadIdx.x;
  const int wave = tid >> 6, lane = tid & 63;
  int bn, bm;
  if (SWZ) {
    int bid = blockIdx.x;
    int xcd = bid & 7, loc = bid >> 3;
    bn = loc % nbn;
    bm = xcd * (nbm >> 3) + loc / nbn;
  } else {
    bn = blockIdx.x;
    bm = blockIdx.y;
  }
  const int bz = blockIdx.z;
  const int wm = (wave >> 1) * 64, wn = (wave & 1) * 64;

  A += (size_t)bz * zA;
  B += (size_t)bz * zB;

  const int r0 = tid >> 2;              // row 0..63 (row1 = r0+64)
  const int lg = tid & 3;               // logical 16B group
  const int ps = lg ^ ((r0 >> 1) & 3);  // physical group (same for r0,r0+64)
  int gmA0 = bm * 128 + r0, gmA1 = gmA0 + 64;
  int gnB0 = bn * 128 + r0, gnB1 = gnB0 + 64;
  if (GUARD) {
    gmA0 = gmA0 < M ? gmA0 : M - 1;
    gmA1 = gmA1 < M ? gmA1 : M - 1;
    gnB0 = gnB0 < N ? gnB0 : N - 1;
    gnB1 = gnB1 < N ? gnB1 : N - 1;
  }
  const size_t rb = (size_t)K * 2;
  const char* pa0 = (const char*)A + (size_t)gmA0 * rb + lg * 16;
  const char* pa1 = (const char*)A + (size_t)gmA1 * rb + lg * 16;
  const char* pb0 = (const char*)B + (size_t)gnB0 * rb + lg * 16;
  const char* pb1 = (const char*)B + (size_t)gnB1 * rb + lg * 16;
  const int w0 = r0 * 32 + ps * 8;      // u16 offset in tile; row1 at +2048

  f32x4 acc[4][4];
  const f32x4 z = {0.f, 0.f, 0.f, 0.f};
#pragma unroll
  for (int i = 0; i < 4; ++i)
#pragma unroll
    for (int j = 0; j < 4; ++j) acc[i][j] = z;

  const int r = lane & 15, qd = lane >> 4;
  const int pA = (qd ^ ((lane >> 1) & 3)) * 8;   // fragment physical group
  const int nk = K >> 5;

  uint4 va0, va1, vb0, vb1;             // tile staged in SCALAR registers
  auto gload = [&](int kt) {
    const size_t ko = (size_t)kt * 64;
    va0 = *(const uint4*)(pa0 + ko);
    va1 = *(const uint4*)(pa1 + ko);
    vb0 = *(const uint4*)(pb0 + ko);
    vb1 = *(const uint4*)(pb1 + ko);
  };

  gload(0);
  int pg = 0;
  for (int kt = 0; kt < nk; ++kt) {
    *(uint4*)&sA[pg][w0]        = va0;
    *(uint4*)&sA[pg][w0 + 2048] = va1;
    *(uint4*)&sB[pg][w0]        = vb0;
    *(uint4*)&sB[pg][w0 + 2048] = vb1;
    if (kt + 1 < nk) gload(kt + 1);   // next tile flies during MFMA below
    __syncthreads();                  // drains lgkm (ds_write), not vmcnt
    bf16x8 af[4], bg[4];
#pragma unroll
    for (int mi = 0; mi < 4; ++mi)
      af[mi] = *(const bf16x8*)&sA[pg][(wm + mi * 16 + r) * 32 + pA];
#pragma unroll
    for (int ni = 0; ni < 4; ++ni)
      bg[ni] = *(const bf16x8*)&sB[pg][(wn + ni * 16 + r) * 32 + pA];
#pragma unroll
    for (int mi = 0; mi < 4; ++mi)
#pragma unroll
      for (int ni = 0; ni < 4; ++ni)
        acc[mi][ni] = mfma16<!TRANS>(af[mi], bg[ni], acc[mi][ni]);
    pg ^= 1;
  }

  if (Cf) Cf += (size_t)bz * zC;
  if (Cb) Cb += (size_t)bz * zC;

  if constexpr (!TRANS) {
    // swapped orientation: lane holds row gm = ..+r, 4 consecutive gn.
#pragma unroll
    for (int mi = 0; mi < 4; ++mi) {
      const int gm = bm * 128 + wm + mi * 16 + r;
      if (GUARD && gm >= M) continue;
#pragma unroll
      for (int ni = 0; ni < 4; ++ni) {
        const int gn0 = bn * 128 + wn + ni * 16 + qd * 4;
        if (GUARD && gn0 >= N) continue;
        float v[4];
        ushort4 rv;
        if (RES) rv = *(const ushort4*)&res[(size_t)gm * N + gn0];
#pragma unroll
        for (int e = 0; e < 4; ++e) {
          v[e] = acc[mi][ni][e];
          if (BIAS) v[e] += bias[gn0 + e];
          if (RES)  v[e] += b2f(e == 0 ? rv.x : e == 1 ? rv.y : e == 2 ? rv.z : rv.w);
          if (RELU) v[e] = v[e] > 0.f ? v[e] : 0.f;
        }
        if (OUTBF16) {
          ushort4 o;
          o.x = f2b(v[0]); o.y = f2b(v[1]); o.z = f2b(v[2]); o.w = f2b(v[3]);
          *(ushort4*)&Cb[(size_t)gm * N + gn0] = o;
        } else {
          float4 o = {v[0], v[1], v[2], v[3]};
          *(float4*)&Cf[(size_t)gm * N + gn0] = o;
        }
      }
    }
  } else {
    // original orientation: lane holds col gn = ..+r, 4 consecutive gm;
    // TRANS store C[gn*M + gm] packs along gm.
#pragma unroll
    for (int ni = 0; ni < 4; ++ni) {
      const int gn = bn * 128 + wn + ni * 16 + r;
      if (GUARD && gn >= N) continue;
      const float bb = BIAS ? bias[gn] : 0.f;
#pragma unroll
      for (int mi = 0; mi < 4; ++mi) {
        const int gm0 = bm * 128 + wm + mi * 16 + qd * 4;
        if (GUARD && gm0 >= M) continue;
        float v[4];
#pragma unroll
        for (int e = 0; e < 4; ++e) {
          v[e] = acc[mi][ni][e];
          if (BIAS) v[e] += bb;
          if (RELU) v[e] = v[e] > 0.f ? v[e] : 0.f;
        }
        if (OUTBF16) {
          ushort4 o;
          o.x = f2b(v[0]); o.y = f2b(v[1]); o.z = f2b(v[2]); o.w = f2b(v[3]);
          *(ushort4*)&Cb[(size_t)gn * M + gm0] = o;
        } else {
          float4 o = {v[0], v[1], v[2], v[3]};
          *(float4*)&Cf[(size_t)gn * M + gm0] = o;
        }
      }
    }
  }
}

// ---------------- 256x256 4-phase deep-pipelined bf16 GEMM -----------------
// R14-EXACT (measured-best config).  C = A(MxK)*B(NxK)^T (+bias)(+res)(relu),
// bf16 out.  BM=BN=256, BK=64, 512 threads = 8 waves (2Mx4N), per-wave
// 128x64 (acc[8][4]).  LDS 128KB: [2 dbuf][2 ksub][256x32], R9 XOR swizzle.
// Per K-tile: 4 quadrant phases; each: ds_read | 1 half-tile stage (2 gll16)
// | counted vmcnt(8) | barrier | setprio 16 MFMA | barrier.  Tail: vmcnt(4)
// at (nk-2,ph3), vmcnt(0) at (nk-1,ph1).
template<bool BIAS, bool RELU, bool RES, bool TRANS>
__global__ __launch_bounds__(512, 2)
void k_gemm3(const u16* __restrict__ A, const u16* __restrict__ B,
             const float* __restrict__ bias, const u16* __restrict__ res,
             u16* __restrict__ C, int M, int N, int K,
             int nbn, int nbm, long zA, long zC)
{
  __shared__ __align__(16) u16 sA[2][2][256 * 32];
  __shared__ __align__(16) u16 sB[2][2][256 * 32];
  const int tid = threadIdx.x;
  const int w8 = tid >> 6, lane = tid & 63;
  const int bid = blockIdx.x;
  const int xcd = bid & 7, loc = bid >> 3;
  const int mpx = (int)(gridDim.x >> 3) / nbn;   // m-groups per XCD
  const int mflat = xcd * mpx + loc / nbn;
  const int bn = loc % nbn;
  const int bz = mflat / nbm;
  const int bm = mflat - bz * nbm;
  const int wm = (w8 >> 2) * 128, wn = (w8 & 3) * 64;

  A += (size_t)bz * zA;

  const int r0 = tid >> 2;
  const int lg = (tid & 3) ^ ((r0 >> 1) & 3);    // same for r0 and r0+128
  const u16* pA0 = A + (size_t)(bm * 256 + r0) * K + lg * 8;
  const u16* pA1 = pA0 + (size_t)128 * K;
  const u16* pB0 = B + (size_t)(bn * 256 + r0) * K + lg * 8;
  const u16* pB1 = pB0 + (size_t)128 * K;
  const int la0 = w8 * 512;          // u16 offset of wave chunk, rows 0-127
  const int la1 = 4096 + w8 * 512;   // rows 128-255

  const int nk = K >> 6;

  auto stA = [&](int t, int ks) {
    const size_t ko = (size_t)(t << 6) + (size_t)(ks << 5);
    u16* d = &sA[t & 1][ks][0];
    gll16(pA0 + ko, d + la0);
    gll16(pA1 + ko, d + la1);
  };
  auto stB = [&](int t, int ks) {
    const size_t ko = (size_t)(t << 6) + (size_t)(ks << 5);
    u16* d = &sB[t & 1][ks][0];
    gll16(pB0 + ko, d + la0);
    gll16(pB1 + ko, d + la1);
  };

  f32x4 acc[8][4];
  const f32x4 z = {0.f, 0.f, 0.f, 0.f};
#pragma unroll
  for (int i = 0; i < 8; ++i)
#pragma unroll
    for (int j = 0; j < 4; ++j) acc[i][j] = z;

  const int fr = lane & 15, qd = lane >> 4;
  const int pAo = ((qd ^ ((lane >> 1) & 3)) << 3);   // fragment phys group

  // prologue: tile0 fully + tile1's k0 halves (6 stages = 12 gll)
  stA(0, 0); stB(0, 0); stA(0, 1); stB(0, 1);
  if (nk > 1) { stA(1, 0); stB(1, 0); }
  asm volatile("s_waitcnt vmcnt(8)" ::: "memory");   // tile0 k0 halves landed
  __builtin_amdgcn_s_barrier();

  for (int t = 0; t < nk; ++t) {
    const int c = t & 1;
    bf16x8 af[4], bgk[4];
    // ---- phase 0: quadrant (mh0, ks0); stage A_k1(t+1) ----
#pragma unroll
    for (int i = 0; i < 4; ++i)
      af[i] = *(const bf16x8*)&sA[c][0][(wm + i * 16 + fr) * 32 + pAo];
#pragma unroll
    for (int i = 0; i < 4; ++i)
      bgk[i] = *(const bf16x8*)&sB[c][0][(wn + i * 16 + fr) * 32 + pAo];
    if (t + 1 < nk) stA(t + 1, 1);
    asm volatile("s_waitcnt vmcnt(8)" ::: "memory");
    __builtin_amdgcn_s_barrier();
    __builtin_amdgcn_s_setprio(1);
#pragma unroll
    for (int mi = 0; mi < 4; ++mi)
#pragma unroll
      for (int ni = 0; ni < 4; ++ni)
        acc[mi][ni] = __builtin_amdgcn_mfma_f32_16x16x32_bf16(
            af[mi], bgk[ni], acc[mi][ni], 0, 0, 0);
    __builtin_amdgcn_s_setprio(0);
    __builtin_amdgcn_s_barrier();
    // ---- phase 1: quadrant (mh1, ks0); stage B_k1(t+1) ----
#pragma unroll
    for (int i = 0; i < 4; ++i)
      af[i] = *(const bf16x8*)&sA[c][0][(wm + 64 + i * 16 + fr) * 32 + pAo];
    if (t + 1 < nk) stB(t + 1, 1);
    if (t == nk - 1) asm volatile("s_waitcnt vmcnt(0)" ::: "memory");
    else             asm volatile("s_waitcnt vmcnt(8)" ::: "memory");
    __builtin_amdgcn_s_barrier();
    __builtin_amdgcn_s_setprio(1);
#pragma unroll
    for (int mi = 0; mi < 4; ++mi)
#pragma unroll
      for (int ni = 0; ni < 4; ++ni)
        acc[4 + mi][ni] = __builtin_amdgcn_mfma_f32_16x16x32_bf16(
            af[mi], bgk[ni], acc[4 + mi][ni], 0, 0, 0);
    __builtin_amdgcn_s_setprio(0);
    __builtin_amdgcn_s_barrier();
    // ---- phase 2: quadrant (mh0, ks1); stage A_k0(t+2) ----
#pragma unroll
    for (int i = 0; i < 4; ++i)
      af[i] = *(const bf16x8*)&sA[c][1][(wm + i * 16 + fr) * 32 + pAo];
#pragma unroll
    for (int i = 0; i < 4; ++i)
      bgk[i] = *(const bf16x8*)&sB[c][1][(wn + i * 16 + fr) * 32 + pAo];
    if (t + 2 < nk) stA(t + 2, 0);
    asm volatile("s_waitcnt vmcnt(8)" ::: "memory");
    __builtin_amdgcn_s_barrier();
    __builtin_amdgcn_s_setprio(1);
#pragma unroll
    for (int mi = 0; mi < 4; ++mi)
#pragma unroll
      for (int ni = 0; ni < 4; ++ni)
        acc[mi][ni] = __builtin_amdgcn_mfma_f32_16x16x32_bf16(
            af[mi], bgk[ni], acc[mi][ni], 0, 0, 0);
    __builtin_amdgcn_s_setprio(0);
    __builtin_amdgcn_s_barrier();
    // ---- phase 3: quadrant (mh1, ks1); stage B_k0(t+2) ----
#pragma unroll
    for (int i = 0; i < 4; ++i)
      af[i] = *(const bf16x8*)&sA[c][1][(wm + 64 + i * 16 + fr) * 32 + pAo];
    if (t + 2 < nk) stB(t + 2, 0);
    if (t == nk - 2) asm volatile("s_waitcnt vmcnt(4)" ::: "memory");
    else             asm volatile("s_waitcnt vmcnt(8)" ::: "memory");
    __builtin_amdgcn_s_barrier();
    __builtin_amdgcn_s_setprio(1);
#pragma unroll
    for (int mi = 0; mi < 4; ++mi)
#pragma unroll
      for (int ni = 0; ni < 4; ++ni)
        acc[4 + mi][ni] = __builtin_amdgcn_mfma_f32_16x16x32_bf16(
            af[mi], bgk[ni], acc[4 + mi][ni], 0, 0, 0);
    __builtin_amdgcn_s_setprio(0);
    __builtin_amdgcn_s_barrier();
  }

  C += (size_t)bz * zC;
#pragma unroll
  for (int mi = 0; mi < 8; ++mi) {
#pragma unroll
    for (int ni = 0; ni < 4; ++ni) {
#pragma unroll
      for (int e = 0; e < 4; ++e) {
        int gm = bm * 256 + wm + mi * 16 + qd * 4 + e;
        int gn = bn * 256 + wn + ni * 16 + fr;
        float v = acc[mi][ni][e];
        if (BIAS) v += bias[gn];
        if (RES)  v += b2f(res[(size_t)gm * N + gn]);
        if (RELU) v = v > 0.f ? v : 0.f;
        size_t oi = TRANS ? ((size_t)gn * M + gm) : ((size_t)gm * N + gn);
        C[oi] = f2b(v);
      }
    }
  }
}

// ---------------- misc small kernels ----------------
__global__ void k_basis(u16* __restrict__ dftB, u16* __restrict__ Binv)
{
  int id = blockIdx.x * 256 + threadIdx.x;  // 32768
  if (id >= 32768) return;
  {
    int m = id >> 9, l = id & 511;
    int mm = m & 31;
    float ang = (float)((l * mm) & 511) * (6.283185307179586f / 512.f);
    float s, c;
    __sincosf(ang, &s, &c);
    dftB[id] = f2b(m < 32 ? c : -s);
  }
  {
    int l = id >> 6, m = id & 63;
    int mm = m & 31;
    float ang = (float)((l * mm) & 511) * (6.283185307179586f / 512.f);
    float s, c;
    __sincosf(ang, &s, &c);
    float v;
    if (m < 32) v = (m == 0 ? 1.f : 2.f) * (1.f / 512.f) * c;
    else        v = (mm == 0 ? 0.f : (-2.f / 512.f) * s);
    Binv[id] = f2b(v);
  }
}

// WB[layer][d'][m] = sum_l Wo[layer][d'][l] * b2f(Binv[l*64+m]), bf16 out.
// 1024 blocks (layer*512 + d'), 256 threads: m = t&63, l-quarter = t>>6.
__global__ void k_wb(const float* __restrict__ wo, const u16* __restrict__ Binv,
                     u16* __restrict__ wb)
{
  __shared__ float part[4][64];
  int blk = blockIdx.x;
  int t = threadIdx.x;
  int m = t & 63, q = t >> 6;
  const float* wrow = wo + (size_t)blk * 512;
  float a = 0.f;
#pragma unroll 4
  for (int l = q * 128; l < q * 128 + 128; ++l)
    a += wrow[l] * b2f(Binv[l * 64 + m]);
  part[q][m] = a;
  __syncthreads();
  if (t < 64) {
    float v = part[0][t] + part[1][t] + part[2][t] + part[3][t];
    wb[(size_t)blk * 64 + t] = f2b(v);
  }
}

// merged weight converts: Wq(512K) | c1(2M) | c2(2M) f32->bf16
__global__ void k_convert3(const float* __restrict__ wq, u16* __restrict__ wqo,
                           const float* __restrict__ c1, u16* __restrict__ c1o,
                           const float* __restrict__ c2, u16* __restrict__ c2o)
{
  int id = blockIdx.x * 256 + threadIdx.x;       // 4718592 total
  if (id < 524288)       wqo[id]           = f2b(wq[id]);
  else if (id < 2621440) c1o[id - 524288]  = f2b(c1[id - 524288]);
  else                   c2o[id - 2621440] = f2b(c2[id - 2621440]);
}

__global__ void k_convproj(const float* __restrict__ w, u16* __restrict__ o)
{
  int id = blockIdx.x * 256 + threadIdx.x;  // 10000*544
  if (id >= 10000 * 544) return;
  int n = id / 544, k = id % 544;
  o[id] = f2b(k < 536 ? w[(size_t)n * 536 + k] : 0.f);
}

// weight transpose for mode mix: wrT[((l*8+h)*32+m)][i][o], LDS pad 33.
__global__ void k_transp(const float* __restrict__ wr, const float* __restrict__ wi,
                         float* __restrict__ wrT, float* __restrict__ wiT)
{
  __shared__ float tr[64 * 33], ti[64 * 33];
  int blk = blockIdx.x;            // (l*8+h)*64+i, 1024 blocks
  int t = threadIdx.x;
  int lh = blk >> 6, i = blk & 63;
  const size_t src = (size_t)blk * 2048;   // o*32+m slab
#pragma unroll
  for (int p = 0; p < 8; ++p) {
    int id = p * 256 + t;
    int o = id >> 5, m = id & 31;
    tr[o * 33 + m] = wr[src + id];
    ti[o * 33 + m] = wi[src + id];
  }
  __syncthreads();
#pragma unroll
  for (int p = 0; p < 8; ++p) {
    int id = p * 256 + t;
    int m = id >> 6, o = id & 63;
    size_t dst = ((size_t)(lh * 32 + m) * 64 + i) * 64 + o;
    wrT[dst] = tr[o * 33 + m];
    wiT[dst] = ti[o * 33 + m];
  }
}

__global__ void k_embed(const int* __restrict__ xapp, const float* __restrict__ xtime,
                        const float* __restrict__ emb, const float* __restrict__ tw,
                        const float* __restrict__ tb, u16* __restrict__ xb)
{
  int id = blockIdx.x * 256 + threadIdx.x;  // B*L*128 (float4 lanes)
  int j = id & 127, bl = id >> 7;
  float4 e = ((const float4*)emb)[(size_t)xapp[bl] * 128 + j];
  float t = xtime[bl];
  float4 w4 = ((const float4*)tw)[j];
  float4 b4 = ((const float4*)tb)[j];
  ushort4 o;
  o.x = f2b(e.x + t * w4.x + b4.x);
  o.y = f2b(e.y + t * w4.y + b4.y);
  o.z = f2b(e.z + t * w4.z + b4.z);
  o.w = f2b(e.w + t * w4.w + b4.w);
  ((ushort4*)xb)[id] = o;
}

// mode mix: coef[b*512 + h*64+o][m](Re) / [32+m](Im), bf16 A-operand.
__global__ __launch_bounds__(256)
void k_mix(const float* __restrict__ spec, const float* __restrict__ wrT,
           const float* __restrict__ wiT, u16* __restrict__ Ab)
{
  __shared__ float swr[4096], swi[4096];   // [i*64+o]
  __shared__ float sre[4][64], sim[4][64]; // [bsub][i]
  int hm = blockIdx.x;                     // h*32+m
  int bg = blockIdx.y;                     // 0..3
  int h = hm >> 5, m = hm & 31, t = threadIdx.x;
  const float* wrb = wrT + (size_t)hm * 4096;
  const float* wib = wiT + (size_t)hm * 4096;
#pragma unroll
  for (int p = 0; p < 16; ++p) {
    int id = p * 256 + t;
    swr[id] = wrb[id];
    swi[id] = wib[id];
  }
  int o = t & 63, bsub = t >> 6;
  for (int b0 = 0; b0 < 16; b0 += 4) {
    __syncthreads();
    int b = bg * 16 + b0 + bsub;
    const float* spb = spec + (size_t)b * 32768;
    sre[bsub][o] = spb[m * 512 + h * 64 + o];
    sim[bsub][o] = spb[(32 + m) * 512 + h * 64 + o];
    __syncthreads();
    float aR = 0.f, aI = 0.f;
#pragma unroll 8
    for (int i = 0; i < 64; ++i) {
      float xr = sre[bsub][i], xi = sim[bsub][i];
      float wrv = swr[i * 64 + o], wiv = swi[i * 64 + o];
      aR += xr * wrv - xi * wiv;
      aI += xr * wiv + xi * wrv;
    }
    size_t row = (size_t)b * 512 + h * 64 + o;
    Ab[row * 64 + m] = f2b(aR);
    Ab[row * 64 + 32 + m] = f2b(aI);
  }
}

// series_decomp: out = x - movavg_25(x), edge-padded.  bf16 in/out, fp32
// accumulate.  XCD-grouped: all blocks of batch b run on XCD b%8.
__global__ void k_decomp(const u16* __restrict__ in, u16* __restrict__ outb)
{
  int blk = blockIdx.x;                 // 512 blocks
  int j = blk >> 3;
  int b = (blk & 7) + 8 * (j >> 3);     // xcd = b%8
  int ck = (j & 7) * 2 + (threadIdx.x >> 7);
  int d4 = threadIdx.x & 127;
  const ushort4* xb = (const ushort4*)(in + (size_t)b * 262144) + d4;
  ushort4* ob = (ushort4*)(outb + (size_t)b * 262144) + d4;
  int l0 = ck * 32;
  f32x4 sum = {0.f, 0.f, 0.f, 0.f};
#pragma unroll
  for (int jj = -12; jj <= 12; ++jj) {
    int idx = l0 + jj;
    idx = idx < 0 ? 0 : idx;
    sum += b4f(xb[idx * 128]);
  }
#pragma unroll 4
  for (int l = l0; l < l0 + 32; ++l) {
    f32x4 xv = b4f(xb[l * 128]);
    f32x4 o = xv - sum * (1.f / 25.f);
    ushort4 ov;
    ov.x = f2b(o.x); ov.y = f2b(o.y); ov.z = f2b(o.z); ov.w = f2b(o.w);
    ob[l * 128] = ov;
    int ia = l + 13 > 511 ? 511 : l + 13;
    int ir = l - 12 < 0 ? 0 : l - 12;
    sum += b4f(xb[ia * 128]) - b4f(xb[ir * 128]);
  }
}

__global__ void k_lnstats(const u16* __restrict__ x, float* __restrict__ mu,
                          float* __restrict__ rs)
{
  int row = blockIdx.x;
  const u16* xr = x + (size_t)row * 512;
  int t = threadIdx.x;
  ushort2 p = ((const ushort2*)xr)[t];
  float v0 = b2f(p.x), v1 = b2f(p.y);
  float s = v0 + v1, ss = v0 * v0 + v1 * v1;
#pragma unroll
  for (int off = 32; off; off >>= 1) {
    s += __shfl_down(s, off);
    ss += __shfl_down(ss, off);
  }
  __shared__ float as[4], ass[4];
  if ((t & 63) == 0) { as[t >> 6] = s; ass[t >> 6] = ss; }
  __syncthreads();
  if (t == 0) {
    float S = as[0] + as[1] + as[2] + as[3];
    float SS = ass[0] + ass[1] + ass[2] + ass[3];
    float m = S * (1.f / 512.f);
    float var = SS * (1.f / 512.f) - m * m;
    mu[row] = m;
    rs[row] = rsqrtf(var + 1e-5f);
  }
}

// lastcat pass 1: partial[b][g][d] = sum_{l in g*64..} (x-mu)*rs  (512 blocks)
__global__ void k_lastcat1(const u16* __restrict__ x, const float* __restrict__ mu,
                           const float* __restrict__ rs, float* __restrict__ part)
{
  int b = blockIdx.x >> 3, g = blockIdx.x & 7, t = threadIdx.x;
  const u16* xb = x + (size_t)b * 262144;
  const float* mub = mu + b * 512;
  const float* rsb = rs + b * 512;
  float a0 = 0.f, a1 = 0.f;
#pragma unroll 4
  for (int l = g * 64; l < g * 64 + 64; ++l) {
    float m = mub[l], rr = rsb[l];
    ushort2 p = ((const ushort2*)(xb + l * 512))[t];
    a0 += (b2f(p.x) - m) * rr;
    a1 += (b2f(p.y) - m) * rr;
  }
  part[((size_t)b * 8 + g) * 512 + 2 * t]     = a0;
  part[((size_t)b * 8 + g) * 512 + 2 * t + 1] = a1;
}

// lastcat pass 2: cat[b][d] = nw[d]*(ln_last - mean_l);  norm_b cancels.
__global__ void k_lastcat2(const u16* __restrict__ x, const float* __restrict__ mu,
                           const float* __restrict__ rs, const float* __restrict__ part,
                           const float* __restrict__ nw, u16* __restrict__ cat)
{
  int b = blockIdx.x, t = threadIdx.x;
#pragma unroll
  for (int hh = 0; hh < 2; ++hh) {
    int d = t + hh * 256;
    float acc = 0.f;
#pragma unroll
    for (int g = 0; g < 8; ++g)
      acc += part[((size_t)b * 8 + g) * 512 + d];
    float lastv = (b2f(x[(size_t)b * 262144 + 511 * 512 + d]) - mu[b * 512 + 511])
                  * rs[b * 512 + 511];
    cat[b * 544 + d] = f2b(nw[d] * (lastv - acc * (1.f / 512.f)));
  }
}

__global__ void k_timecat(const float* __restrict__ tv, u16* __restrict__ cat)
{
  int id = blockIdx.x * 256 + threadIdx.x;  // 64*32
  if (id >= 2048) return;
  int b = id >> 5, j = id & 31;
  int pos = 512 + j;
  float v = (pos < 536) ? tv[((size_t)b * 512 + 511) * 24 + (pos - 512)] : 0.f;
  cat[b * 544 + pos] = f2b(v);
}

// ---------------------------------------------------------------------------
extern "C" void kernel_launch(void* const* d_in, const int* in_sizes, int n_in,
                              void* d_out, int out_size, void* d_ws, size_t ws_size,
                              hipStream_t stream)
{
  (void)in_sizes; (void)n_in; (void)out_size; (void)ws_size;
  const int*   x_app  = (const int*)  d_in[0];
  const float* x_time = (const float*)d_in[1];
  const float* tvec   = (const float*)d_in[2];
  // d_in[3] targets: unused by reference output
  const float* emb    = (const float*)d_in[4];
  const float* time_w = (const float*)d_in[5];
  const float* time_b = (const float*)d_in[6];
  const float* Wq     = (const float*)d_in[7];
  const float* bq     = (const float*)d_in[8];
  const float* Wo     = (const float*)d_in[9];
  const float* bo     = (const float*)d_in[10];
  const float* fwr    = (const float*)d_in[11];
  const float* fwi    = (const float*)d_in[12];
  const float* c1     = (const float*)d_in[13];
  const float* c2     = (const float*)d_in[14];
  const float* norm_w = (const float*)d_in[15];
  // d_in[16] norm_b: cancels in (xh - mean_l xh)
  const float* proj_w = (const float*)d_in[17];
  const float* proj_b = (const float*)d_in[18];
  float* out = (float*)d_out;

  char* w = (char*)d_ws;
  auto alloc = [&](size_t bytes) -> char* {
    char* p = w;
    w += (bytes + 255) & ~(size_t)255;
    return p;
  };
  // Workspace ~261 MB
  u16*   Cb   = (u16*)  alloc(33554432);          // x / x1 / x2 bf16
  u16*   YqT  = (u16*)  alloc(134217728);         // qT / conv1-out
  u16*   T1b  = (u16*)  alloc(33554432);          // t1 / t2 bf16
  float* S1   = (float*)alloc(8388608);           // spec (B,64,D) fp32
  u16*   Coef = (u16*)  alloc(4194304);           // mixed spectrum bf16
  float* wrT  = (float*)alloc(2 * 1048576 * 4);   // mix weights transposed
  float* wiT  = (float*)alloc(2 * 1048576 * 4);
  u16*   wqb  = (u16*)  alloc(2 * 262144 * 2);
  u16*   wbb  = (u16*)  alloc(2 * 512 * 64 * 2);  // WB = Wo @ Binv, bf16
  u16*   c1b  = (u16*)  alloc(2 * 1048576 * 2);
  u16*   c2b  = (u16*)  alloc(2 * 1048576 * 2);
  u16*   pwb  = (u16*)  alloc(10000 * 544 * 2);
  u16*   dftB = (u16*)  alloc(64 * 512 * 2);
  u16*   Binv = (u16*)  alloc(512 * 64 * 2);
  float* muB  = (float*)alloc(131072);
  float* rsB  = (float*)alloc(131072);
  float* part = (float*)alloc(64 * 8 * 512 * 4);  // lastcat partials
  u16*   cat  = (u16*)  alloc(64 * 544 * 2);

  k_basis<<<128, 256, 0, stream>>>(dftB, Binv);
  k_wb<<<1024, 256, 0, stream>>>(Wo, Binv, wbb);  // after k_basis (Binv dep)
  k_transp<<<1024, 256, 0, stream>>>(fwr, fwi, wrT, wiT);
  k_convert3<<<18432, 256, 0, stream>>>(Wq, wqb, c1, c1b, c2, c2b);
  k_convproj<<<21250, 256, 0, stream>>>(proj_w, pwb);
  k_embed<<<16384, 256, 0, stream>>>(x_app, x_time, emb, time_w, time_b, Cb);

  for (int l = 0; l < 2; ++l) {
    const u16* wq_l = wqb + l * 262144;
    const u16* wb_l = wbb + l * 32768;
    const u16* c1_l = c1b + l * 1048576;
    const u16* c2_l = c2b + l * 1048576;

    // qT[b][d][l] = (x @ Wq^T + bq)^T, bf16, batched over bz, TRANS store
    // grid 256 = nbn(2) * nbm(2) * 64 batches, XCD-grouped
    k_gemm3<true, false, false, true>
        <<<256, 512, 0, stream>>>(
        Cb, wq_l, bq + l * 512, nullptr, YqT, 512, 512, 512,
        2, 2, 262144, 262144);
    // spec[b][m][d] = qT[b] @ dftB^T  (M=512,N=64 pad 128,K=512), TRANS store
    k_gemm<false, false, false, false, true, true, false>
        <<<dim3(1, 4, 64), 256, 0, stream>>>(
        YqT, dftB, nullptr, nullptr, S1, nullptr, 512, 64, 512,
        262144, 0, 32768, 0, 0);
    k_mix<<<dim3(256, 4), 256, 0, stream>>>(
        S1, wrT + l * 1048576, wiT + l * 1048576, Coef);
    // FUSED iDFT*Wo: t1 = Coef @ (Wo@Binv)^T + bo + x  (M=32768,N=512,K=64)
    // row (b,rho) matches the reference's (B,H,E,L)->(B,L,D) flat reshape.
    k_gemm<true, false, true, true, false, false, true>
        <<<dim3(1024, 1, 1), 256, 0, stream>>>(
        Coef, wb_l, bo + l * 512, Cb, nullptr, T1b, 32768, 512, 64,
        0, 0, 0, 4, 256);
    k_decomp<<<512, 256, 0, stream>>>(T1b, Cb);     // x1 bf16
    // y = relu(x1 @ c1^T) -> bf16  (M=32768, N=2048, single dispatch)
    k_gemm3<false, true, false, false>
        <<<1024, 512, 0, stream>>>(
        Cb, c1_l, nullptr, nullptr, YqT, 32768, 2048, 512,
        8, 128, 0, 0);
    // t2 = y @ c2^T + x1  (res = Cb bf16) -> T1b bf16
    k_gemm3<false, false, true, false>
        <<<256, 512, 0, stream>>>(
        YqT, c2_l, nullptr, Cb, T1b, 32768, 512, 2048,
        2, 128, 0, 0);
    k_decomp<<<512, 256, 0, stream>>>(T1b, Cb);     // next-layer x bf16
  }

  k_lnstats<<<32768, 256, 0, stream>>>(Cb, muB, rsB);
  k_lastcat1<<<512, 256, 0, stream>>>(Cb, muB, rsB, part);
  k_lastcat2<<<64, 256, 0, stream>>>(Cb, muB, rsB, part, norm_w, cat);
  k_timecat<<<8, 256, 0, stream>>>(tvec, cat);
  // score = cat @ proj_w^T + proj_b   (K padded 536->544 with zeros)
  k_gemm<true, false, false, false, true, false, false>
      <<<dim3(79, 1, 1), 256, 0, stream>>>(
      cat, pwb, proj_b, nullptr, out, nullptr, 64, 10000, 544,
      0, 0, 0, 0, 0);
}

// Round 10
// 763.026 us; speedup vs baseline: 3.0298x; 1.0556x over previous
//
#include <hip/hip_runtime.h>

// ---------------------------------------------------------------------------
// AppUsageFEDformer forward on MI355X (gfx950).
// embed -> 2x [Wq gemm(->qT bf16) -> DFT-GEMM -> mix -> FUSED (iDFT*Wo) gemm
//              (+res) -> decomp -> conv1(relu) -> conv2(+res) -> decomp]
//          -> layernorm(+L-mean sub) -> last-token concat -> proj gemm.
// R20->R21: k_gemm3 K-loop rebuilt to the m201 single-barrier discipline.
// R20 accounting: per K-tile/SIMD MFMA=2483cyc, LDS reads~2300cyc, measured
// 7000cyc -> pipes SERIALIZED by the 8-barrier/K-tile structure (all waves
// start read-bursts simultaneously after the post-MFMA barrier).  m201 hits
// 3300cyc with identical geometry via: reads issued BEFORE the (single)
// barrier -- early waves' reads execute under other waves' MFMA -- plus
// full-tile-lead staging and counted vmcnt at 2 points/K-tile.
// New loop: stages re-mapped to tile t+1 (targets last read a full tile ago,
// >=2 barriers -- safer than old t+2 map); per K-tile 2 barriers:
//  {reads(mh0,ks)+stageA(t+1,ks) | MFMA | reads(mh1)+stageB(t+1,ks) |
//   vmcnt(4) | barrier | MFMA} x {ks=0,1}.  Tail vmcnt(0) at (nk-1,half0).
// Fragment layout, staging geometry, epilogue, per-element MFMA k-order all
// unchanged -> bit-identical output.  Everything else kept from R20 (805us):
// iDFT*Wo fusion, packed k_gemm epilogues, merged converts, XCD swizzles.
// ---------------------------------------------------------------------------

typedef unsigned short u16;
typedef float f32x4 __attribute__((ext_vector_type(4)));
typedef __bf16 bf16x8 __attribute__((ext_vector_type(8)));

__device__ __forceinline__ u16 f2b(float f) {
  unsigned u = __float_as_uint(f);
  return (u16)((u + 0x7FFFu + ((u >> 16) & 1u)) >> 16);
}
__device__ __forceinline__ float b2f(u16 v) {
  return __uint_as_float((unsigned)v << 16);
}
__device__ __forceinline__ f32x4 b4f(ushort4 v) {
  f32x4 r;
  r.x = b2f(v.x); r.y = b2f(v.y); r.z = b2f(v.z); r.w = b2f(v.w);
  return r;
}

__device__ __forceinline__ void gll16(const void* g, void* l) {
  __builtin_amdgcn_global_load_lds(
      (const __attribute__((address_space(1))) void*)g,
      (__attribute__((address_space(3))) void*)l, 16, 0, 0);
}

// SWAP=true computes mfma(b,a): D'[n][m] = sum_k B[n][k]A[m][k] = C[m][n];
// lane then holds row m = lane&15, cols n = (lane>>4)*4+e.  Values are the
// same dot products in the same HW order -> bit-identical per element.
template<bool SWAP>
__device__ __forceinline__ f32x4 mfma16(bf16x8 a, bf16x8 b, f32x4 c) {
  if constexpr (SWAP)
    return __builtin_amdgcn_mfma_f32_16x16x32_bf16(b, a, c, 0, 0, 0);
  else
    return __builtin_amdgcn_mfma_f32_16x16x32_bf16(a, b, c, 0, 0, 0);
}

// ---------------- bf16 MFMA GEMM:  C = A(MxK) * B(NxK)^T (+bias)(+res)(relu)
// 128x128 tile, BK=32.  R9-proven scalar-register 1-deep pipeline.  Used for
// small/odd shapes (DFT N=64 guard, fused iDFT*Wo K=64, proj M=64 K=544).
// Epilogue packs 4 values per store (swapped MFMA for !TRANS) -- R16/R19-
// verified.
template<bool BIAS, bool RELU, bool RES, bool OUTBF16, bool GUARD, bool TRANS,
         bool SWZ>
__global__ __launch_bounds__(256, 3)
void k_gemm(const u16* __restrict__ A, const u16* __restrict__ B,
            const float* __restrict__ bias, const u16* __restrict__ res,
            float* __restrict__ Cf, u16* __restrict__ Cb,
            int M, int N, int K,
            long zA, long zB, long zC, int nbn, int nbm)
{
  __shared__ __align__(16) u16 sA[2][128 * 32];
  __shared__ __align__(16) u16 sB[2][128 * 32];
  const int tid = threadIdx.x;
  const int wave = tid >> 6, lane = tid & 63;
  int bn, bm;
  if (SWZ) {
    int bid = blockIdx.x;
    int xcd = bid & 7, loc = bid >> 3;
    bn = loc % nbn;
    bm = xcd * (nbm >> 3) + loc / nbn;
  } else {
    bn = blockIdx.x;
    bm = blockIdx.y;
  }
  const int bz = blockIdx.z;
  const int wm = (wave >> 1) * 64, wn = (wave & 1) * 64;

  A += (size_t)bz * zA;
  B += (size_t)bz * zB;

  const int r0 = tid >> 2;              // row 0..63 (row1 = r0+64)
  const int lg = tid & 3;               // logical 16B group
  const int ps = lg ^ ((r0 >> 1) & 3);  // physical group (same for r0,r0+64)
  int gmA0 = bm * 128 + r0, gmA1 = gmA0 + 64;
  int gnB0 = bn * 128 + r0, gnB1 = gnB0 + 64;
  if (GUARD) {
    gmA0 = gmA0 < M ? gmA0 : M - 1;
    gmA1 = gmA1 < M ? gmA1 : M - 1;
    gnB0 = gnB0 < N ? gnB0 : N - 1;
    gnB1 = gnB1 < N ? gnB1 : N - 1;
  }
  const size_t rb = (size_t)K * 2;
  const char* pa0 = (const char*)A + (size_t)gmA0 * rb + lg * 16;
  const char* pa1 = (const char*)A + (size_t)gmA1 * rb + lg * 16;
  const char* pb0 = (const char*)B + (size_t)gnB0 * rb + lg * 16;
  const char* pb1 = (const char*)B + (size_t)gnB1 * rb + lg * 16;
  const int w0 = r0 * 32 + ps * 8;      // u16 offset in tile; row1 at +2048

  f32x4 acc[4][4];
  const f32x4 z = {0.f, 0.f, 0.f, 0.f};
#pragma unroll
  for (int i = 0; i < 4; ++i)
#pragma unroll
    for (int j = 0; j < 4; ++j) acc[i][j] = z;

  const int r = lane & 15, qd = lane >> 4;
  const int pA = (qd ^ ((lane >> 1) & 3)) * 8;   // fragment physical group
  const int nk = K >> 5;

  uint4 va0, va1, vb0, vb1;             // tile staged in SCALAR registers
  auto gload = [&](int kt) {
    const size_t ko = (size_t)kt * 64;
    va0 = *(const uint4*)(pa0 + ko);
    va1 = *(const uint4*)(pa1 + ko);
    vb0 = *(const uint4*)(pb0 + ko);
    vb1 = *(const uint4*)(pb1 + ko);
  };

  gload(0);
  int pg = 0;
  for (int kt = 0; kt < nk; ++kt) {
    *(uint4*)&sA[pg][w0]        = va0;
    *(uint4*)&sA[pg][w0 + 2048] = va1;
    *(uint4*)&sB[pg][w0]        = vb0;
    *(uint4*)&sB[pg][w0 + 2048] = vb1;
    if (kt + 1 < nk) gload(kt + 1);   // next tile flies during MFMA below
    __syncthreads();                  // drains lgkm (ds_write), not vmcnt
    bf16x8 af[4], bg[4];
#pragma unroll
    for (int mi = 0; mi < 4; ++mi)
      af[mi] = *(const bf16x8*)&sA[pg][(wm + mi * 16 + r) * 32 + pA];
#pragma unroll
    for (int ni = 0; ni < 4; ++ni)
      bg[ni] = *(const bf16x8*)&sB[pg][(wn + ni * 16 + r) * 32 + pA];
#pragma unroll
    for (int mi = 0; mi < 4; ++mi)
#pragma unroll
      for (int ni = 0; ni < 4; ++ni)
        acc[mi][ni] = mfma16<!TRANS>(af[mi], bg[ni], acc[mi][ni]);
    pg ^= 1;
  }

  if (Cf) Cf += (size_t)bz * zC;
  if (Cb) Cb += (size_t)bz * zC;

  if constexpr (!TRANS) {
    // swapped orientation: lane holds row gm = ..+r, 4 consecutive gn.
#pragma unroll
    for (int mi = 0; mi < 4; ++mi) {
      const int gm = bm * 128 + wm + mi * 16 + r;
      if (GUARD && gm >= M) continue;
#pragma unroll
      for (int ni = 0; ni < 4; ++ni) {
        const int gn0 = bn * 128 + wn + ni * 16 + qd * 4;
        if (GUARD && gn0 >= N) continue;
        float v[4];
        ushort4 rv;
        if (RES) rv = *(const ushort4*)&res[(size_t)gm * N + gn0];
#pragma unroll
        for (int e = 0; e < 4; ++e) {
          v[e] = acc[mi][ni][e];
          if (BIAS) v[e] += bias[gn0 + e];
          if (RES)  v[e] += b2f(e == 0 ? rv.x : e == 1 ? rv.y : e == 2 ? rv.z : rv.w);
          if (RELU) v[e] = v[e] > 0.f ? v[e] : 0.f;
        }
        if (OUTBF16) {
          ushort4 o;
          o.x = f2b(v[0]); o.y = f2b(v[1]); o.z = f2b(v[2]); o.w = f2b(v[3]);
          *(ushort4*)&Cb[(size_t)gm * N + gn0] = o;
        } else {
          float4 o = {v[0], v[1], v[2], v[3]};
          *(float4*)&Cf[(size_t)gm * N + gn0] = o;
        }
      }
    }
  } else {
    // original orientation: lane holds col gn = ..+r, 4 consecutive gm;
    // TRANS store C[gn*M + gm] packs along gm.
#pragma unroll
    for (int ni = 0; ni < 4; ++ni) {
      const int gn = bn * 128 + wn + ni * 16 + r;
      if (GUARD && gn >= N) continue;
      const float bb = BIAS ? bias[gn] : 0.f;
#pragma unroll
      for (int mi = 0; mi < 4; ++mi) {
        const int gm0 = bm * 128 + wm + mi * 16 + qd * 4;
        if (GUARD && gm0 >= M) continue;
        float v[4];
#pragma unroll
        for (int e = 0; e < 4; ++e) {
          v[e] = acc[mi][ni][e];
          if (BIAS) v[e] += bb;
          if (RELU) v[e] = v[e] > 0.f ? v[e] : 0.f;
        }
        if (OUTBF16) {
          ushort4 o;
          o.x = f2b(v[0]); o.y = f2b(v[1]); o.z = f2b(v[2]); o.w = f2b(v[3]);
          *(ushort4*)&Cb[(size_t)gn * M + gm0] = o;
        } else {
          float4 o = {v[0], v[1], v[2], v[3]};
          *(float4*)&Cf[(size_t)gn * M + gm0] = o;
        }
      }
    }
  }
}

// ---------------- 256x256 single-barrier-phase bf16 GEMM -------------------
// C = A(MxK)*B(NxK)^T (+bias)(+res)(relu), bf16 out.  BM=BN=256, BK=64,
// 512 threads = 8 waves (2Mx4N), per-wave 128x64 (acc[8][4]).  LDS 128KB:
// [2 dbuf][2 ksub][256x32], R9 XOR source swizzle.  m201-style loop:
// per K-tile 2 barriers; per half-tile ks:
//   reads(mh0,ks)+bg | stage A(t+1,ks) | MFMA mh0 | reads(mh1) |
//   stage B(t+1,ks) | vmcnt(4) | barrier | MFMA mh1.
// Reads are issued BEFORE the barrier (under other waves' MFMA); staged
// buffers have a FULL-TILE lead (target last read >=2 barriers ago); the
// vmcnt(4)+barrier pair confirms the next half-tile's data before its reads.
// Tail: vmcnt(0) at (nk-1, half0).  1D grid, XCD-grouped decode.
template<bool BIAS, bool RELU, bool RES, bool TRANS>
__global__ __launch_bounds__(512, 2)
void k_gemm3(const u16* __restrict__ A, const u16* __restrict__ B,
             const float* __restrict__ bias, const u16* __restrict__ res,
             u16* __restrict__ C, int M, int N, int K,
             int nbn, int nbm, long zA, long zC)
{
  __shared__ __align__(16) u16 sA[2][2][256 * 32];
  __shared__ __align__(16) u16 sB[2][2][256 * 32];
  const int tid = threadIdx.x;
  const int w8 = tid >> 6, lane = tid & 63;
  const int bid = blockIdx.x;
  const int xcd = bid & 7, loc = bid >> 3;
  const int mpx = (int)(gridDim.x >> 3) / nbn;   // m-groups per XCD
  const int mflat = xcd * mpx + loc / nbn;
  const int bn = loc % nbn;
  const int bz = mflat / nbm;
  const int bm = mflat - bz * nbm;
  const int wm = (w8 >> 2) * 128, wn = (w8 & 3) * 64;

  A += (size_t)bz * zA;

  const int r0 = tid >> 2;
  const int lg = (tid & 3) ^ ((r0 >> 1) & 3);    // same for r0 and r0+128
  const u16* pA0 = A + (size_t)(bm * 256 + r0) * K + lg * 8;
  const u16* pA1 = pA0 + (size_t)128 * K;
  const u16* pB0 = B + (size_t)(bn * 256 + r0) * K + lg * 8;
  const u16* pB1 = pB0 + (size_t)128 * K;
  const int la0 = w8 * 512;          // u16 offset of wave chunk, rows 0-127
  const int la1 = 4096 + w8 * 512;   // rows 128-255

  const int nk = K >> 6;

  auto stA = [&](int t, int ks) {
    const size_t ko = (size_t)(t << 6) + (size_t)(ks << 5);
    u16* d = &sA[t & 1][ks][0];
    gll16(pA0 + ko, d + la0);
    gll16(pA1 + ko, d + la1);
  };
  auto stB = [&](int t, int ks) {
    const size_t ko = (size_t)(t << 6) + (size_t)(ks << 5);
    u16* d = &sB[t & 1][ks][0];
    gll16(pB0 + ko, d + la0);
    gll16(pB1 + ko, d + la1);
  };

  f32x4 acc[8][4];
  const f32x4 z = {0.f, 0.f, 0.f, 0.f};
#pragma unroll
  for (int i = 0; i < 8; ++i)
#pragma unroll
    for (int j = 0; j < 4; ++j) acc[i][j] = z;

  const int fr = lane & 15, qd = lane >> 4;
  const int pAo = ((qd ^ ((lane >> 1) & 3)) << 3);   // fragment phys group

  // prologue: tile 0 fully staged; confirm k0 halves before first reads.
  stA(0, 0); stB(0, 0); stA(0, 1); stB(0, 1);
  asm volatile("s_waitcnt vmcnt(4)" ::: "memory");
  __builtin_amdgcn_s_barrier();
  asm volatile("" ::: "memory");

  for (int t = 0; t < nk; ++t) {
    const int c = t & 1;
    bf16x8 af[4], bgk[4];
    // ================= half 0 (ks0) =================
#pragma unroll
    for (int i = 0; i < 4; ++i)
      af[i] = *(const bf16x8*)&sA[c][0][(wm + i * 16 + fr) * 32 + pAo];
#pragma unroll
    for (int i = 0; i < 4; ++i)
      bgk[i] = *(const bf16x8*)&sB[c][0][(wn + i * 16 + fr) * 32 + pAo];
    if (t + 1 < nk) stA(t + 1, 0);
    __builtin_amdgcn_s_setprio(1);
#pragma unroll
    for (int mi = 0; mi < 4; ++mi)
#pragma unroll
      for (int ni = 0; ni < 4; ++ni)
        acc[mi][ni] = __builtin_amdgcn_mfma_f32_16x16x32_bf16(
            af[mi], bgk[ni], acc[mi][ni], 0, 0, 0);
    __builtin_amdgcn_s_setprio(0);
#pragma unroll
    for (int i = 0; i < 4; ++i)
      af[i] = *(const bf16x8*)&sA[c][0][(wm + 64 + i * 16 + fr) * 32 + pAo];
    if (t + 1 < nk) stB(t + 1, 0);
    // confirm A/B(t, ks1) landed (staged last tile / prologue)
    if (t == nk - 1) asm volatile("s_waitcnt vmcnt(0)" ::: "memory");
    else             asm volatile("s_waitcnt vmcnt(4)" ::: "memory");
    __builtin_amdgcn_s_barrier();
    asm volatile("" ::: "memory");
    __builtin_amdgcn_s_setprio(1);
#pragma unroll
    for (int mi = 0; mi < 4; ++mi)
#pragma unroll
      for (int ni = 0; ni < 4; ++ni)
        acc[4 + mi][ni] = __builtin_amdgcn_mfma_f32_16x16x32_bf16(
            af[mi], bgk[ni], acc[4 + mi][ni], 0, 0, 0);
    __builtin_amdgcn_s_setprio(0);
    // ================= half 1 (ks1) =================
#pragma unroll
    for (int i = 0; i < 4; ++i)
      af[i] = *(const bf16x8*)&sA[c][1][(wm + i * 16 + fr) * 32 + pAo];
#pragma unroll
    for (int i = 0; i < 4; ++i)
      bgk[i] = *(const bf16x8*)&sB[c][1][(wn + i * 16 + fr) * 32 + pAo];
    if (t + 1 < nk) stA(t + 1, 1);
    __builtin_amdgcn_s_setprio(1);
#pragma unroll
    for (int mi = 0; mi < 4; ++mi)
#pragma unroll
      for (int ni = 0; ni < 4; ++ni)
        acc[mi][ni] = __builtin_amdgcn_mfma_f32_16x16x32_bf16(
            af[mi], bgk[ni], acc[mi][ni], 0, 0, 0);
    __builtin_amdgcn_s_setprio(0);
#pragma unroll
    for (int i = 0; i < 4; ++i)
      af[i] = *(const bf16x8*)&sA[c][1][(wm + 64 + i * 16 + fr) * 32 + pAo];
    if (t + 1 < nk) stB(t + 1, 1);
    // confirm A/B(t+1, ks0) landed for next tile's half-0 reads
    if (t + 1 < nk) asm volatile("s_waitcnt vmcnt(4)" ::: "memory");
    __builtin_amdgcn_s_barrier();
    asm volatile("" ::: "memory");
    __builtin_amdgcn_s_setprio(1);
#pragma unroll
    for (int mi = 0; mi < 4; ++mi)
#pragma unroll
      for (int ni = 0; ni < 4; ++ni)
        acc[4 + mi][ni] = __builtin_amdgcn_mfma_f32_16x16x32_bf16(
            af[mi], bgk[ni], acc[4 + mi][ni], 0, 0, 0);
    __builtin_amdgcn_s_setprio(0);
  }

  C += (size_t)bz * zC;
#pragma unroll
  for (int mi = 0; mi < 8; ++mi) {
#pragma unroll
    for (int ni = 0; ni < 4; ++ni) {
#pragma unroll
      for (int e = 0; e < 4; ++e) {
        int gm = bm * 256 + wm + mi * 16 + qd * 4 + e;
        int gn = bn * 256 + wn + ni * 16 + fr;
        float v = acc[mi][ni][e];
        if (BIAS) v += bias[gn];
        if (RES)  v += b2f(res[(size_t)gm * N + gn]);
        if (RELU) v = v > 0.f ? v : 0.f;
        size_t oi = TRANS ? ((size_t)gn * M + gm) : ((size_t)gm * N + gn);
        C[oi] = f2b(v);
      }
    }
  }
}

// ---------------- misc small kernels ----------------
__global__ void k_basis(u16* __restrict__ dftB, u16* __restrict__ Binv)
{
  int id = blockIdx.x * 256 + threadIdx.x;  // 32768
  if (id >= 32768) return;
  {
    int m = id >> 9, l = id & 511;
    int mm = m & 31;
    float ang = (float)((l * mm) & 511) * (6.283185307179586f / 512.f);
    float s, c;
    __sincosf(ang, &s, &c);
    dftB[id] = f2b(m < 32 ? c : -s);
  }
  {
    int l = id >> 6, m = id & 63;
    int mm = m & 31;
    float ang = (float)((l * mm) & 511) * (6.283185307179586f / 512.f);
    float s, c;
    __sincosf(ang, &s, &c);
    float v;
    if (m < 32) v = (m == 0 ? 1.f : 2.f) * (1.f / 512.f) * c;
    else        v = (mm == 0 ? 0.f : (-2.f / 512.f) * s);
    Binv[id] = f2b(v);
  }
}

// WB[layer][d'][m] = sum_l Wo[layer][d'][l] * b2f(Binv[l*64+m]), bf16 out.
// 1024 blocks (layer*512 + d'), 256 threads: m = t&63, l-quarter = t>>6.
__global__ void k_wb(const float* __restrict__ wo, const u16* __restrict__ Binv,
                     u16* __restrict__ wb)
{
  __shared__ float part[4][64];
  int blk = blockIdx.x;
  int t = threadIdx.x;
  int m = t & 63, q = t >> 6;
  const float* wrow = wo + (size_t)blk * 512;
  float a = 0.f;
#pragma unroll 4
  for (int l = q * 128; l < q * 128 + 128; ++l)
    a += wrow[l] * b2f(Binv[l * 64 + m]);
  part[q][m] = a;
  __syncthreads();
  if (t < 64) {
    float v = part[0][t] + part[1][t] + part[2][t] + part[3][t];
    wb[(size_t)blk * 64 + t] = f2b(v);
  }
}

// merged weight converts: Wq(512K) | c1(2M) | c2(2M) f32->bf16
__global__ void k_convert3(const float* __restrict__ wq, u16* __restrict__ wqo,
                           const float* __restrict__ c1, u16* __restrict__ c1o,
                           const float* __restrict__ c2, u16* __restrict__ c2o)
{
  int id = blockIdx.x * 256 + threadIdx.x;       // 4718592 total
  if (id < 524288)       wqo[id]           = f2b(wq[id]);
  else if (id < 2621440) c1o[id - 524288]  = f2b(c1[id - 524288]);
  else                   c2o[id - 2621440] = f2b(c2[id - 2621440]);
}

__global__ void k_convproj(const float* __restrict__ w, u16* __restrict__ o)
{
  int id = blockIdx.x * 256 + threadIdx.x;  // 10000*544
  if (id >= 10000 * 544) return;
  int n = id / 544, k = id % 544;
  o[id] = f2b(k < 536 ? w[(size_t)n * 536 + k] : 0.f);
}

// weight transpose for mode mix: wrT[((l*8+h)*32+m)][i][o], LDS pad 33.
__global__ void k_transp(const float* __restrict__ wr, const float* __restrict__ wi,
                         float* __restrict__ wrT, float* __restrict__ wiT)
{
  __shared__ float tr[64 * 33], ti[64 * 33];
  int blk = blockIdx.x;            // (l*8+h)*64+i, 1024 blocks
  int t = threadIdx.x;
  int lh = blk >> 6, i = blk & 63;
  const size_t src = (size_t)blk * 2048;   // o*32+m slab
#pragma unroll
  for (int p = 0; p < 8; ++p) {
    int id = p * 256 + t;
    int o = id >> 5, m = id & 31;
    tr[o * 33 + m] = wr[src + id];
    ti[o * 33 + m] = wi[src + id];
  }
  __syncthreads();
#pragma unroll
  for (int p = 0; p < 8; ++p) {
    int id = p * 256 + t;
    int m = id >> 6, o = id & 63;
    size_t dst = ((size_t)(lh * 32 + m) * 64 + i) * 64 + o;
    wrT[dst] = tr[o * 33 + m];
    wiT[dst] = ti[o * 33 + m];
  }
}

__global__ void k_embed(const int* __restrict__ xapp, const float* __restrict__ xtime,
                        const float* __restrict__ emb, const float* __restrict__ tw,
                        const float* __restrict__ tb, u16* __restrict__ xb)
{
  int id = blockIdx.x * 256 + threadIdx.x;  // B*L*128 (float4 lanes)
  int j = id & 127, bl = id >> 7;
  float4 e = ((const float4*)emb)[(size_t)xapp[bl] * 128 + j];
  float t = xtime[bl];
  float4 w4 = ((const float4*)tw)[j];
  float4 b4 = ((const float4*)tb)[j];
  ushort4 o;
  o.x = f2b(e.x + t * w4.x + b4.x);
  o.y = f2b(e.y + t * w4.y + b4.y);
  o.z = f2b(e.z + t * w4.z + b4.z);
  o.w = f2b(e.w + t * w4.w + b4.w);
  ((ushort4*)xb)[id] = o;
}

// mode mix: coef[b*512 + h*64+o][m](Re) / [32+m](Im), bf16 A-operand.
__global__ __launch_bounds__(256)
void k_mix(const float* __restrict__ spec, const float* __restrict__ wrT,
           const float* __restrict__ wiT, u16* __restrict__ Ab)
{
  __shared__ float swr[4096], swi[4096];   // [i*64+o]
  __shared__ float sre[4][64], sim[4][64]; // [bsub][i]
  int hm = blockIdx.x;                     // h*32+m
  int bg = blockIdx.y;                     // 0..3
  int h = hm >> 5, m = hm & 31, t = threadIdx.x;
  const float* wrb = wrT + (size_t)hm * 4096;
  const float* wib = wiT + (size_t)hm * 4096;
#pragma unroll
  for (int p = 0; p < 16; ++p) {
    int id = p * 256 + t;
    swr[id] = wrb[id];
    swi[id] = wib[id];
  }
  int o = t & 63, bsub = t >> 6;
  for (int b0 = 0; b0 < 16; b0 += 4) {
    __syncthreads();
    int b = bg * 16 + b0 + bsub;
    const float* spb = spec + (size_t)b * 32768;
    sre[bsub][o] = spb[m * 512 + h * 64 + o];
    sim[bsub][o] = spb[(32 + m) * 512 + h * 64 + o];
    __syncthreads();
    float aR = 0.f, aI = 0.f;
#pragma unroll 8
    for (int i = 0; i < 64; ++i) {
      float xr = sre[bsub][i], xi = sim[bsub][i];
      float wrv = swr[i * 64 + o], wiv = swi[i * 64 + o];
      aR += xr * wrv - xi * wiv;
      aI += xr * wiv + xi * wrv;
    }
    size_t row = (size_t)b * 512 + h * 64 + o;
    Ab[row * 64 + m] = f2b(aR);
    Ab[row * 64 + 32 + m] = f2b(aI);
  }
}

// series_decomp: out = x - movavg_25(x), edge-padded.  bf16 in/out, fp32
// accumulate.  XCD-grouped: all blocks of batch b run on XCD b%8.
__global__ void k_decomp(const u16* __restrict__ in, u16* __restrict__ outb)
{
  int blk = blockIdx.x;                 // 512 blocks
  int j = blk >> 3;
  int b = (blk & 7) + 8 * (j >> 3);     // xcd = b%8
  int ck = (j & 7) * 2 + (threadIdx.x >> 7);
  int d4 = threadIdx.x & 127;
  const ushort4* xb = (const ushort4*)(in + (size_t)b * 262144) + d4;
  ushort4* ob = (ushort4*)(outb + (size_t)b * 262144) + d4;
  int l0 = ck * 32;
  f32x4 sum = {0.f, 0.f, 0.f, 0.f};
#pragma unroll
  for (int jj = -12; jj <= 12; ++jj) {
    int idx = l0 + jj;
    idx = idx < 0 ? 0 : idx;
    sum += b4f(xb[idx * 128]);
  }
#pragma unroll 4
  for (int l = l0; l < l0 + 32; ++l) {
    f32x4 xv = b4f(xb[l * 128]);
    f32x4 o = xv - sum * (1.f / 25.f);
    ushort4 ov;
    ov.x = f2b(o.x); ov.y = f2b(o.y); ov.z = f2b(o.z); ov.w = f2b(o.w);
    ob[l * 128] = ov;
    int ia = l + 13 > 511 ? 511 : l + 13;
    int ir = l - 12 < 0 ? 0 : l - 12;
    sum += b4f(xb[ia * 128]) - b4f(xb[ir * 128]);
  }
}

__global__ void k_lnstats(const u16* __restrict__ x, float* __restrict__ mu,
                          float* __restrict__ rs)
{
  int row = blockIdx.x;
  const u16* xr = x + (size_t)row * 512;
  int t = threadIdx.x;
  ushort2 p = ((const ushort2*)xr)[t];
  float v0 = b2f(p.x), v1 = b2f(p.y);
  float s = v0 + v1, ss = v0 * v0 + v1 * v1;
#pragma unroll
  for (int off = 32; off; off >>= 1) {
    s += __shfl_down(s, off);
    ss += __shfl_down(ss, off);
  }
  __shared__ float as[4], ass[4];
  if ((t & 63) == 0) { as[t >> 6] = s; ass[t >> 6] = ss; }
  __syncthreads();
  if (t == 0) {
    float S = as[0] + as[1] + as[2] + as[3];
    float SS = ass[0] + ass[1] + ass[2] + ass[3];
    float m = S * (1.f / 512.f);
    float var = SS * (1.f / 512.f) - m * m;
    mu[row] = m;
    rs[row] = rsqrtf(var + 1e-5f);
  }
}

// lastcat pass 1: partial[b][g][d] = sum_{l in g*64..} (x-mu)*rs  (512 blocks)
__global__ void k_lastcat1(const u16* __restrict__ x, const float* __restrict__ mu,
                           const float* __restrict__ rs, float* __restrict__ part)
{
  int b = blockIdx.x >> 3, g = blockIdx.x & 7, t = threadIdx.x;
  const u16* xb = x + (size_t)b * 262144;
  const float* mub = mu + b * 512;
  const float* rsb = rs + b * 512;
  float a0 = 0.f, a1 = 0.f;
#pragma unroll 4
  for (int l = g * 64; l < g * 64 + 64; ++l) {
    float m = mub[l], rr = rsb[l];
    ushort2 p = ((const ushort2*)(xb + l * 512))[t];
    a0 += (b2f(p.x) - m) * rr;
    a1 += (b2f(p.y) - m) * rr;
  }
  part[((size_t)b * 8 + g) * 512 + 2 * t]     = a0;
  part[((size_t)b * 8 + g) * 512 + 2 * t + 1] = a1;
}

// lastcat pass 2: cat[b][d] = nw[d]*(ln_last - mean_l);  norm_b cancels.
__global__ void k_lastcat2(const u16* __restrict__ x, const float* __restrict__ mu,
                           const float* __restrict__ rs, const float* __restrict__ part,
                           const float* __restrict__ nw, u16* __restrict__ cat)
{
  int b = blockIdx.x, t = threadIdx.x;
#pragma unroll
  for (int hh = 0; hh < 2; ++hh) {
    int d = t + hh * 256;
    float acc = 0.f;
#pragma unroll
    for (int g = 0; g < 8; ++g)
      acc += part[((size_t)b * 8 + g) * 512 + d];
    float lastv = (b2f(x[(size_t)b * 262144 + 511 * 512 + d]) - mu[b * 512 + 511])
                  * rs[b * 512 + 511];
    cat[b * 544 + d] = f2b(nw[d] * (lastv - acc * (1.f / 512.f)));
  }
}

__global__ void k_timecat(const float* __restrict__ tv, u16* __restrict__ cat)
{
  int id = blockIdx.x * 256 + threadIdx.x;  // 64*32
  if (id >= 2048) return;
  int b = id >> 5, j = id & 31;
  int pos = 512 + j;
  float v = (pos < 536) ? tv[((size_t)b * 512 + 511) * 24 + (pos - 512)] : 0.f;
  cat[b * 544 + pos] = f2b(v);
}

// ---------------------------------------------------------------------------
extern "C" void kernel_launch(void* const* d_in, const int* in_sizes, int n_in,
                              void* d_out, int out_size, void* d_ws, size_t ws_size,
                              hipStream_t stream)
{
  (void)in_sizes; (void)n_in; (void)out_size; (void)ws_size;
  const int*   x_app  = (const int*)  d_in[0];
  const float* x_time = (const float*)d_in[1];
  const float* tvec   = (const float*)d_in[2];
  // d_in[3] targets: unused by reference output
  const float* emb    = (const float*)d_in[4];
  const float* time_w = (const float*)d_in[5];
  const float* time_b = (const float*)d_in[6];
  const float* Wq     = (const float*)d_in[7];
  const float* bq     = (const float*)d_in[8];
  const float* Wo     = (const float*)d_in[9];
  const float* bo     = (const float*)d_in[10];
  const float* fwr    = (const float*)d_in[11];
  const float* fwi    = (const float*)d_in[12];
  const float* c1     = (const float*)d_in[13];
  const float* c2     = (const float*)d_in[14];
  const float* norm_w = (const float*)d_in[15];
  // d_in[16] norm_b: cancels in (xh - mean_l xh)
  const float* proj_w = (const float*)d_in[17];
  const float* proj_b = (const float*)d_in[18];
  float* out = (float*)d_out;

  char* w = (char*)d_ws;
  auto alloc = [&](size_t bytes) -> char* {
    char* p = w;
    w += (bytes + 255) & ~(size_t)255;
    return p;
  };
  // Workspace ~261 MB
  u16*   Cb   = (u16*)  alloc(33554432);          // x / x1 / x2 bf16
  u16*   YqT  = (u16*)  alloc(134217728);         // qT / conv1-out
  u16*   T1b  = (u16*)  alloc(33554432);          // t1 / t2 bf16
  float* S1   = (float*)alloc(8388608);           // spec (B,64,D) fp32
  u16*   Coef = (u16*)  alloc(4194304);           // mixed spectrum bf16
  float* wrT  = (float*)alloc(2 * 1048576 * 4);   // mix weights transposed
  float* wiT  = (float*)alloc(2 * 1048576 * 4);
  u16*   wqb  = (u16*)  alloc(2 * 262144 * 2);
  u16*   wbb  = (u16*)  alloc(2 * 512 * 64 * 2);  // WB = Wo @ Binv, bf16
  u16*   c1b  = (u16*)  alloc(2 * 1048576 * 2);
  u16*   c2b  = (u16*)  alloc(2 * 1048576 * 2);
  u16*   pwb  = (u16*)  alloc(10000 * 544 * 2);
  u16*   dftB = (u16*)  alloc(64 * 512 * 2);
  u16*   Binv = (u16*)  alloc(512 * 64 * 2);
  float* muB  = (float*)alloc(131072);
  float* rsB  = (float*)alloc(131072);
  float* part = (float*)alloc(64 * 8 * 512 * 4);  // lastcat partials
  u16*   cat  = (u16*)  alloc(64 * 544 * 2);

  k_basis<<<128, 256, 0, stream>>>(dftB, Binv);
  k_wb<<<1024, 256, 0, stream>>>(Wo, Binv, wbb);  // after k_basis (Binv dep)
  k_transp<<<1024, 256, 0, stream>>>(fwr, fwi, wrT, wiT);
  k_convert3<<<18432, 256, 0, stream>>>(Wq, wqb, c1, c1b, c2, c2b);
  k_convproj<<<21250, 256, 0, stream>>>(proj_w, pwb);
  k_embed<<<16384, 256, 0, stream>>>(x_app, x_time, emb, time_w, time_b, Cb);

  for (int l = 0; l < 2; ++l) {
    const u16* wq_l = wqb + l * 262144;
    const u16* wb_l = wbb + l * 32768;
    const u16* c1_l = c1b + l * 1048576;
    const u16* c2_l = c2b + l * 1048576;

    // qT[b][d][l] = (x @ Wq^T + bq)^T, bf16, batched over bz, TRANS store
    // grid 256 = nbn(2) * nbm(2) * 64 batches, XCD-grouped
    k_gemm3<true, false, false, true>
        <<<256, 512, 0, stream>>>(
        Cb, wq_l, bq + l * 512, nullptr, YqT, 512, 512, 512,
        2, 2, 262144, 262144);
    // spec[b][m][d] = qT[b] @ dftB^T  (M=512,N=64 pad 128,K=512), TRANS store
    k_gemm<false, false, false, false, true, true, false>
        <<<dim3(1, 4, 64), 256, 0, stream>>>(
        YqT, dftB, nullptr, nullptr, S1, nullptr, 512, 64, 512,
        262144, 0, 32768, 0, 0);
    k_mix<<<dim3(256, 4), 256, 0, stream>>>(
        S1, wrT + l * 1048576, wiT + l * 1048576, Coef);
    // FUSED iDFT*Wo: t1 = Coef @ (Wo@Binv)^T + bo + x  (M=32768,N=512,K=64)
    k_gemm<true, false, true, true, false, false, true>
        <<<dim3(1024, 1, 1), 256, 0, stream>>>(
        Coef, wb_l, bo + l * 512, Cb, nullptr, T1b, 32768, 512, 64,
        0, 0, 0, 4, 256);
    k_decomp<<<512, 256, 0, stream>>>(T1b, Cb);     // x1 bf16
    // y = relu(x1 @ c1^T) -> bf16  (M=32768, N=2048, single dispatch)
    k_gemm3<false, true, false, false>
        <<<1024, 512, 0, stream>>>(
        Cb, c1_l, nullptr, nullptr, YqT, 32768, 2048, 512,
        8, 128, 0, 0);
    // t2 = y @ c2^T + x1  (res = Cb bf16) -> T1b bf16
    k_gemm3<false, false, true, false>
        <<<256, 512, 0, stream>>>(
        YqT, c2_l, nullptr, Cb, T1b, 32768, 512, 2048,
        2, 128, 0, 0);
    k_decomp<<<512, 256, 0, stream>>>(T1b, Cb);     // next-layer x bf16
  }

  k_lnstats<<<32768, 256, 0, stream>>>(Cb, muB, rsB);
  k_lastcat1<<<512, 256, 0, stream>>>(Cb, muB, rsB, part);
  k_lastcat2<<<64, 256, 0, stream>>>(Cb, muB, rsB, part, norm_w, cat);
  k_timecat<<<8, 256, 0, stream>>>(tvec, cat);
  // score = cat @ proj_w^T + proj_b   (K padded 536->544 with zeros)
  k_gemm<true, false, false, false, true, false, false>
      <<<dim3(79, 1, 1), 256, 0, stream>>>(
      cat, pwb, proj_b, nullptr, out, nullptr, 64, 10000, 544,
      0, 0, 0, 0, 0);
}